// Round 1
// baseline (2945.572 us; speedup 1.0000x reference)
//
#include <hip/hip_runtime.h>
#include <hip/hip_bf16.h>
#include <math.h>

// Problem constants (fixed by the reference)
#define NSEQ   10000
#define NPAD   10240
#define PADR   240
#define HEADS  8
#define DH     64
#define LM     256      // landmarks
#define LFAC   40       // npad / landmarks
#define DMODEL 512
#define DQK    256
#define OUTSZ  20001    // 1 + 10000 + 10000

// ---------------------------------------------------------------------------
// Generic 64x64 tiled fp32 GEMM, C = A(MxK) @ B(KxN), row-major, with fused
// epilogues selected by MODE. A has `pad_rows` virtual zero rows prepended.
//  MODE 0: QKV — split cols into q/k/v head layout [h][row][d]; q scaled 0.125
//  MODE 1: C = acc + bias[c] + extra[r,c]            (w_out -> enc)
//  MODE 2: C = acc                                    (plain, qe/ke)
//  MODE 3: xo epilogue (alpha, sigmoid gating, enc)   (value -> xo)
// ---------------------------------------------------------------------------
template<int MODE>
__global__ __launch_bounds__(256)
void sgemm_k(const float* __restrict__ A, const float* __restrict__ B,
             int M, int N, int K, int pad_rows,
             float* __restrict__ C,
             const float* __restrict__ bias,
             const float* __restrict__ extra,
             const float* __restrict__ alpha,
             float* __restrict__ Qo, float* __restrict__ Ko, float* __restrict__ Vo)
{
    __shared__ float As[16][65];
    __shared__ float Bs[16][65];
    const int tid  = threadIdx.x;
    const int row0 = blockIdx.y * 64;
    const int col0 = blockIdx.x * 64;
    const int ar = tid >> 2, ac = (tid & 3) << 2;   // A tile: 64 rows x 16 cols
    const int br = tid >> 4, bc = (tid & 15) << 2;  // B tile: 16 rows x 64 cols
    const int ty = tid >> 4, tx = tid & 15;
    float acc[4][4] = {};
    for (int k0 = 0; k0 < K; k0 += 16) {
        {
            int r = row0 + ar;
            float4 av = make_float4(0.f, 0.f, 0.f, 0.f);
            if (r < M) {
                int rr = r - pad_rows;
                if (rr >= 0) av = *(const float4*)(A + (size_t)rr * K + (k0 + ac));
            }
            As[ac+0][ar] = av.x; As[ac+1][ar] = av.y;
            As[ac+2][ar] = av.z; As[ac+3][ar] = av.w;
        }
        {
            float4 bv = *(const float4*)(B + (size_t)(k0 + br) * N + (col0 + bc));
            Bs[br][bc+0] = bv.x; Bs[br][bc+1] = bv.y;
            Bs[br][bc+2] = bv.z; Bs[br][bc+3] = bv.w;
        }
        __syncthreads();
        #pragma unroll
        for (int kk = 0; kk < 16; ++kk) {
            float a0 = As[kk][ty*4+0], a1 = As[kk][ty*4+1];
            float a2 = As[kk][ty*4+2], a3 = As[kk][ty*4+3];
            float b0 = Bs[kk][tx*4+0], b1 = Bs[kk][tx*4+1];
            float b2 = Bs[kk][tx*4+2], b3 = Bs[kk][tx*4+3];
            acc[0][0]+=a0*b0; acc[0][1]+=a0*b1; acc[0][2]+=a0*b2; acc[0][3]+=a0*b3;
            acc[1][0]+=a1*b0; acc[1][1]+=a1*b1; acc[1][2]+=a1*b2; acc[1][3]+=a1*b3;
            acc[2][0]+=a2*b0; acc[2][1]+=a2*b1; acc[2][2]+=a2*b2; acc[2][3]+=a2*b3;
            acc[3][0]+=a3*b0; acc[3][1]+=a3*b1; acc[3][2]+=a3*b2; acc[3][3]+=a3*b3;
        }
        __syncthreads();
    }
    #pragma unroll
    for (int i = 0; i < 4; ++i) {
        int r = row0 + ty*4 + i;
        if (r >= M) continue;
        #pragma unroll
        for (int j = 0; j < 4; ++j) {
            int c = col0 + tx*4 + j;
            if (c >= N) continue;
            float v = acc[i][j];
            if (MODE == 0) {
                int t = c >> 9, h = (c >> 6) & 7, d = c & 63;
                float* dst = (t == 0 ? Qo : (t == 1 ? Ko : Vo));
                dst[((size_t)h * NPAD + r) * DH + d] = (t == 0 ? v * 0.125f : v);
            } else if (MODE == 1) {
                C[(size_t)r * N + c] = v + bias[c] + extra[(size_t)r * N + c];
            } else if (MODE == 2) {
                C[(size_t)r * N + c] = v;
            } else if (MODE == 3) {
                float xl = alpha[r] * (v + bias[c]);
                float s  = 1.f / (1.f + expf(xl));   // sigmoid(-xl)
                float w2 = s * s;
                C[(size_t)r * N + c] = 2.f*xl*w2 + 2.f*extra[(size_t)r * N + c]*(1.f - w2);
            }
        }
    }
}

// Batched (8 heads) 256x256 @ 256xN GEMM for the pinv iterations.
// PMODE 0: C = P ; PMODE 1: C = 0.25*P
template<int PMODE>
__global__ __launch_bounds__(256)
void bgemm_k(const float* __restrict__ Ain, const float* __restrict__ Bin,
             float* __restrict__ Cout, int N)
{
    const int h = blockIdx.z;
    const float* A = Ain + (size_t)h * LM * LM;
    const float* B = Bin + (size_t)h * LM * N;
    float*       C = Cout + (size_t)h * LM * N;
    __shared__ float As[16][65];
    __shared__ float Bs[16][65];
    const int tid  = threadIdx.x;
    const int row0 = blockIdx.y * 64;
    const int col0 = blockIdx.x * 64;
    const int ar = tid >> 2, ac = (tid & 3) << 2;
    const int br = tid >> 4, bc = (tid & 15) << 2;
    const int ty = tid >> 4, tx = tid & 15;
    float acc[4][4] = {};
    for (int k0 = 0; k0 < LM; k0 += 16) {
        {
            float4 av = *(const float4*)(A + (size_t)(row0 + ar) * LM + (k0 + ac));
            As[ac+0][ar] = av.x; As[ac+1][ar] = av.y;
            As[ac+2][ar] = av.z; As[ac+3][ar] = av.w;
        }
        {
            float4 bv = *(const float4*)(B + (size_t)(k0 + br) * N + (col0 + bc));
            Bs[br][bc+0] = bv.x; Bs[br][bc+1] = bv.y;
            Bs[br][bc+2] = bv.z; Bs[br][bc+3] = bv.w;
        }
        __syncthreads();
        #pragma unroll
        for (int kk = 0; kk < 16; ++kk) {
            float a0 = As[kk][ty*4+0], a1 = As[kk][ty*4+1];
            float a2 = As[kk][ty*4+2], a3 = As[kk][ty*4+3];
            float b0 = Bs[kk][tx*4+0], b1 = Bs[kk][tx*4+1];
            float b2 = Bs[kk][tx*4+2], b3 = Bs[kk][tx*4+3];
            acc[0][0]+=a0*b0; acc[0][1]+=a0*b1; acc[0][2]+=a0*b2; acc[0][3]+=a0*b3;
            acc[1][0]+=a1*b0; acc[1][1]+=a1*b1; acc[1][2]+=a1*b2; acc[1][3]+=a1*b3;
            acc[2][0]+=a2*b0; acc[2][1]+=a2*b1; acc[2][2]+=a2*b2; acc[2][3]+=a2*b3;
            acc[3][0]+=a3*b0; acc[3][1]+=a3*b1; acc[3][2]+=a3*b2; acc[3][3]+=a3*b3;
        }
        __syncthreads();
    }
    #pragma unroll
    for (int i = 0; i < 4; ++i) {
        int r = row0 + ty*4 + i;
        #pragma unroll
        for (int j = 0; j < 4; ++j) {
            int c = col0 + tx*4 + j;
            float v = acc[i][j];
            C[(size_t)r * N + c] = (PMODE == 1) ? 0.25f * v : v;
        }
    }
}

// Out = c*I - In (elementwise over 8 x 256 x 256; In may equal Out)
__global__ void imsub_k(const float* __restrict__ In, float* __restrict__ Out, float c)
{
    int h = blockIdx.y, i = blockIdx.x, j = threadIdx.x;
    size_t idx = ((size_t)h * LM + i) * LM + j;
    Out[idx] = (i == j ? c : 0.f) - In[idx];
}

// landmark means: dst[h][j][d] = mean_{t<40} src[h][j*40+t][d]
__global__ void landmark_k(const float* __restrict__ src, float* __restrict__ dst)
{
    int b = blockIdx.x;              // h*256 + j
    int h = b >> 8, j = b & 255, d = threadIdx.x;
    const float* p = src + ((size_t)h * NPAD + (size_t)j * LFAC) * DH + d;
    float s = 0.f;
    #pragma unroll
    for (int t = 0; t < LFAC; ++t) s += p[t * DH];
    dst[((size_t)h * LM + j) * DH + d] = s * (1.f / LFAC);
}

// attn2 = softmax(q_l @ k_l^T) per (h, row)
__global__ __launch_bounds__(256)
void attn2_k(const float* __restrict__ QL, const float* __restrict__ KL,
             float* __restrict__ X2)
{
    int i = blockIdx.x, h = blockIdx.y, j = threadIdx.x;
    __shared__ float qv[DH];
    __shared__ float red[256];
    if (j < DH) qv[j] = QL[((size_t)h * LM + i) * DH + j];
    __syncthreads();
    const float* kp = KL + ((size_t)h * LM + j) * DH;
    float dot = 0.f;
    #pragma unroll
    for (int d = 0; d < DH; ++d) dot += qv[d] * kp[d];
    red[j] = dot; __syncthreads();
    for (int s = 128; s > 0; s >>= 1) { if (j < s) red[j] = fmaxf(red[j], red[j+s]); __syncthreads(); }
    float mx = red[0]; __syncthreads();
    float e = expf(dot - mx);
    red[j] = e; __syncthreads();
    for (int s = 128; s > 0; s >>= 1) { if (j < s) red[j] += red[j+s]; __syncthreads(); }
    X2[((size_t)h * LM + i) * LM + j] = e / red[0];
}

// max over row-sums (col) and col-sums (row) of |x| -> two global scalars
__global__ __launch_bounds__(256)
void colrow_k(const float* __restrict__ X2, unsigned int* __restrict__ mx)
{
    int h = blockIdx.x, t = threadIdx.x;
    const float* x = X2 + (size_t)h * LM * LM;
    float cs = 0.f, rs = 0.f;
    for (int j = 0; j < LM; ++j) cs += fabsf(x[(size_t)t * LM + j]);
    for (int i = 0; i < LM; ++i) rs += fabsf(x[(size_t)i * LM + t]);
    __shared__ float r1[256], r2[256];
    r1[t] = cs; r2[t] = rs; __syncthreads();
    for (int s = 128; s > 0; s >>= 1) {
        if (t < s) { r1[t] = fmaxf(r1[t], r1[t+s]); r2[t] = fmaxf(r2[t], r2[t+s]); }
        __syncthreads();
    }
    if (t == 0) {
        atomicMax(&mx[0], __float_as_uint(r1[0]));
        atomicMax(&mx[1], __float_as_uint(r2[0]));
    }
}

// z0 = x^T / (max(col)*max(row))
__global__ void zinit_k(const float* __restrict__ X2, const float* __restrict__ mx,
                        float* __restrict__ Z)
{
    int i = blockIdx.x, h = blockIdx.y, j = threadIdx.x;
    float scale = 1.f / (mx[0] * mx[1]);
    Z[((size_t)h * LM + j) * LM + i] = X2[((size_t)h * LM + i) * LM + j] * scale;
}

// AV[h][i][:] = softmax_j(q_l[h][i] . k[h][j]) @ v[h]   (j over 10240)
__global__ __launch_bounds__(256)
void attn3v_k(const float* __restrict__ QL, const float* __restrict__ Kd,
              const float* __restrict__ V, float* __restrict__ AV)
{
    int i = blockIdx.x, h = blockIdx.y, t = threadIdx.x;
    __shared__ float q[DH];
    __shared__ float red[256];
    __shared__ float pbuf[NPAD];    // 40 KB
    if (t < DH) q[t] = QL[((size_t)h * LM + i) * DH + t];
    __syncthreads();
    float lmax = -INFINITY;
    for (int j = t; j < NPAD; j += 256) {
        const float* kp = Kd + ((size_t)h * NPAD + j) * DH;
        float dot = 0.f;
        #pragma unroll
        for (int d = 0; d < DH; ++d) dot += q[d] * kp[d];
        pbuf[j] = dot;
        lmax = fmaxf(lmax, dot);
    }
    red[t] = lmax; __syncthreads();
    for (int s = 128; s > 0; s >>= 1) { if (t < s) red[t] = fmaxf(red[t], red[t+s]); __syncthreads(); }
    float mx = red[0]; __syncthreads();
    float lsum = 0.f;
    for (int j = t; j < NPAD; j += 256) { float e = expf(pbuf[j] - mx); pbuf[j] = e; lsum += e; }
    red[t] = lsum; __syncthreads();
    for (int s = 128; s > 0; s >>= 1) { if (t < s) red[t] += red[t+s]; __syncthreads(); }
    float inv = 1.f / red[0];
    __syncthreads();
    int d = t & 63, c = t >> 6;     // 4 chunks of 2560 rows
    float acc = 0.f;
    for (int j = c * (NPAD/4); j < (c+1) * (NPAD/4); ++j)
        acc += pbuf[j] * V[((size_t)h * NPAD + j) * DH + d];
    red[t] = acc; __syncthreads();
    if (c == 0)
        AV[((size_t)h * LM + i) * DH + d] = (red[d] + red[d+64] + red[d+128] + red[d+192]) * inv;
}

// out_buf[i][h*64+d] = softmax_j(q[h][i].k_l[h][j]) @ W[h]  +  depthwise conv residual
__global__ __launch_bounds__(256)
void outrows_k(const float* __restrict__ Q, const float* __restrict__ KL,
               const float* __restrict__ W, const float* __restrict__ V,
               const float* __restrict__ cw, float* __restrict__ OB)
{
    int i = blockIdx.x, h = blockIdx.y, t = threadIdx.x;
    __shared__ float q[DH];
    __shared__ float red[256];
    __shared__ float p[LM];
    if (t < DH) q[t] = Q[((size_t)h * NPAD + i) * DH + t];
    __syncthreads();
    const float* kp = KL + ((size_t)h * LM + t) * DH;
    float dot = 0.f;
    #pragma unroll
    for (int d = 0; d < DH; ++d) dot += q[d] * kp[d];
    red[t] = dot; __syncthreads();
    for (int s = 128; s > 0; s >>= 1) { if (t < s) red[t] = fmaxf(red[t], red[t+s]); __syncthreads(); }
    float mx = red[0]; __syncthreads();
    float e = expf(dot - mx);
    p[t] = e;
    red[t] = e; __syncthreads();
    for (int s = 128; s > 0; s >>= 1) { if (t < s) red[t] += red[t+s]; __syncthreads(); }
    float inv = 1.f / red[0];
    __syncthreads();
    int d = t & 63, c = t >> 6;
    float acc = 0.f;
    #pragma unroll
    for (int jj = 0; jj < 64; ++jj) {
        int j = c * 64 + jj;
        acc += p[j] * W[((size_t)h * LM + j) * DH + d];
    }
    red[t] = acc; __syncthreads();
    if (c == 0) {
        float attn = (red[d] + red[d+64] + red[d+128] + red[d+192]) * inv;
        float res = 0.f;
        #pragma unroll
        for (int tt = 0; tt < 33; ++tt) {
            int src = i + tt - 16;
            if (src >= 0 && src < NPAD)
                res += cw[h * 33 + tt] * V[((size_t)h * NPAD + src) * DH + d];
        }
        OB[(size_t)i * DMODEL + h * DH + d] = attn + res;
    }
}

// per-edge dot(qe[row], ke[col]) * val / 16, atomically summed by row
__global__ __launch_bounds__(256)
void edges_k(const int* __restrict__ rows, const int* __restrict__ cols,
             const float* __restrict__ vals,
             const float* __restrict__ QE, const float* __restrict__ KE,
             float* __restrict__ A_raw, int E)
{
    int gid = blockIdx.x * blockDim.x + threadIdx.x;
    int e = gid >> 6, l = gid & 63;
    if (e >= E) return;
    int r = rows[e], c = cols[e];
    const float* qp = QE + (size_t)r * DQK;
    const float* kp = KE + (size_t)c * DQK;
    float dot = 0.f;
    #pragma unroll
    for (int d = l; d < DQK; d += 64) dot += qp[d] * kp[d];
    #pragma unroll
    for (int s = 32; s > 0; s >>= 1) dot += __shfl_down(dot, s);
    if (l == 0) atomicAdd(&A_raw[r], vals[e] * dot * 0.0625f);
}

// alpha = softmax(A_raw) over 10000
__global__ __launch_bounds__(1024)
void alphasm_k(const float* __restrict__ A_raw, float* __restrict__ alpha)
{
    __shared__ float red[1024];
    int t = threadIdx.x;
    float lm = -INFINITY;
    for (int i = t; i < NSEQ; i += 1024) lm = fmaxf(lm, A_raw[i]);
    red[t] = lm; __syncthreads();
    for (int s = 512; s > 0; s >>= 1) { if (t < s) red[t] = fmaxf(red[t], red[t+s]); __syncthreads(); }
    float mx = red[0]; __syncthreads();
    float ls = 0.f;
    for (int i = t; i < NSEQ; i += 1024) ls += expf(A_raw[i] - mx);
    red[t] = ls; __syncthreads();
    for (int s = 512; s > 0; s >>= 1) { if (t < s) red[t] += red[t+s]; __syncthreads(); }
    float inv = 1.f / red[0];
    for (int i = t; i < NSEQ; i += 1024) alpha[i] = expf(A_raw[i] - mx) * inv;
}

// init: out[0]=fc_bias, A_raw region zeroed, k_alpha = 1.0, pinv maxes = 0
__global__ void init_k(float* __restrict__ out, const float* __restrict__ fcb,
                       unsigned int* __restrict__ mx)
{
    int t = blockIdx.x * blockDim.x + threadIdx.x;
    if (t == 0) { out[0] = fcb[0]; mx[0] = 0u; mx[1] = 0u; }
    if (t >= 1 && t <= NSEQ) out[t] = 0.f;
    if (t >= NSEQ + 1 && t < OUTSZ) out[t] = 1.0f;
}

// out[0] += sum_{i,d} xo[i][d] * fc[d]
__global__ __launch_bounds__(256)
void pooled_k(const float* __restrict__ XO, const float* __restrict__ fc,
              float* __restrict__ out0)
{
    __shared__ float red[256];
    int t = threadIdx.x;
    float acc = 0.f;
    const size_t total = (size_t)NSEQ * DMODEL;
    for (size_t idx = (size_t)blockIdx.x * 256 + t; idx < total; idx += (size_t)gridDim.x * 256) {
        int d = (int)(idx & (DMODEL - 1));
        acc += XO[idx] * fc[d];
    }
    red[t] = acc; __syncthreads();
    for (int s = 128; s > 0; s >>= 1) { if (t < s) red[t] += red[t+s]; __syncthreads(); }
    if (t == 0) atomicAdd(out0, red[0]);
}

extern "C" void kernel_launch(void* const* d_in, const int* in_sizes, int n_in,
                              void* d_out, int out_size, void* d_ws, size_t ws_size,
                              hipStream_t stream)
{
    (void)n_in; (void)out_size; (void)ws_size;
    const float* bag   = (const float*)d_in[0];
    const int*   arow  = (const int*)d_in[1];
    const int*   acol  = (const int*)d_in[2];
    const float* aval  = (const float*)d_in[3];
    const float* w_qkv = (const float*)d_in[4];
    const float* w_out = (const float*)d_in[5];
    const float* b_out = (const float*)d_in[6];
    const float* convw = (const float*)d_in[7];
    const float* wq    = (const float*)d_in[8];
    const float* wk    = (const float*)d_in[9];
    const float* wv_w  = (const float*)d_in[10];
    const float* wv_b  = (const float*)d_in[11];
    // d_in[12..14] (v_att, u_att, w_att) are dead: softmax over axis of size 1 == 1
    const float* fck   = (const float*)d_in[15];
    const float* fcb   = (const float*)d_in[16];
    const int E = in_sizes[1];
    float* out = (float*)d_out;

    float* ws = (float*)d_ws;
    size_t off = 0;
    auto alloc = [&](size_t n) { float* p = ws + off; off += n; return p; };
    float* Q   = alloc((size_t)HEADS * NPAD * DH);   // 20 MB
    float* Kd  = alloc((size_t)HEADS * NPAD * DH);
    float* V   = alloc((size_t)HEADS * NPAD * DH);
    float* QL  = alloc((size_t)HEADS * LM * DH);
    float* KL  = alloc((size_t)HEADS * LM * DH);
    float* X2  = alloc((size_t)HEADS * LM * LM);
    float* Za  = alloc((size_t)HEADS * LM * LM);
    float* Zb  = alloc((size_t)HEADS * LM * LM);
    float* T0  = alloc((size_t)HEADS * LM * LM);
    float* T1  = alloc((size_t)HEADS * LM * LM);
    float* Tc  = alloc((size_t)HEADS * LM * LM);
    float* AV  = alloc((size_t)HEADS * LM * DH);
    float* Wb  = alloc((size_t)HEADS * LM * DH);
    float* OB  = alloc((size_t)NPAD * DMODEL);       // 21 MB
    float* MXf = alloc(16);
    float* ALPHA = alloc(10240);
    // aliases (lifetimes disjoint)
    float* ENC = Q;     // 10000x512
    float* QE  = Kd;    // 10000x256
    float* KE  = V;     // 10000x256
    float* XO  = OB;    // 10000x512
    unsigned int* MX = (unsigned int*)MXf;

    // 0) init outputs / scalars
    init_k<<<(OUTSZ + 255) / 256, 256, 0, stream>>>(out, fcb, MX);

    // 1) QKV projection (with 240 virtual zero pad rows), q scaled by 1/8
    sgemm_k<0><<<dim3(1536 / 64, NPAD / 64), 256, 0, stream>>>(
        bag, w_qkv, NPAD, 1536, DMODEL, PADR, nullptr, nullptr, nullptr, nullptr, Q, Kd, V);

    // 2) landmarks
    landmark_k<<<HEADS * LM, DH, 0, stream>>>(Q, QL);
    landmark_k<<<HEADS * LM, DH, 0, stream>>>(Kd, KL);

    // 3) attn2 = softmax(q_l k_l^T); pinv init
    attn2_k<<<dim3(LM, HEADS), 256, 0, stream>>>(QL, KL, X2);
    colrow_k<<<HEADS, 256, 0, stream>>>(X2, MX);
    zinit_k<<<dim3(LM, HEADS), 256, 0, stream>>>(X2, MXf, Za);

    // 4) Newton-Schulz pinv, 6 iterations
    float* zin = Za; float* zout = Zb;
    for (int it = 0; it < 6; ++it) {
        bgemm_k<0><<<dim3(4, 4, HEADS), 256, 0, stream>>>(X2, zin, T0, LM);   // xz
        imsub_k<<<dim3(LM, HEADS), 256, 0, stream>>>(T0, T1, 7.f);            // 7I - xz
        bgemm_k<0><<<dim3(4, 4, HEADS), 256, 0, stream>>>(T0, T1, Tc, LM);    // xz(7I-xz)
        imsub_k<<<dim3(LM, HEADS), 256, 0, stream>>>(Tc, Tc, 15.f);           // 15I - ...
        bgemm_k<0><<<dim3(4, 4, HEADS), 256, 0, stream>>>(T0, Tc, T1, LM);    // xz(15I-...)
        imsub_k<<<dim3(LM, HEADS), 256, 0, stream>>>(T1, T1, 13.f);           // 13I - ...
        bgemm_k<1><<<dim3(4, 4, HEADS), 256, 0, stream>>>(zin, T1, zout, LM); // 0.25 z(...)
        float* tmp = zin; zin = zout; zout = tmp;
    }
    // zin == Za after 6 iterations

    // 5) attn3 @ v (fused softmax over 10240), then W = pinv @ (attn3 v)
    attn3v_k<<<dim3(LM, HEADS), 256, 0, stream>>>(QL, Kd, V, AV);
    bgemm_k<0><<<dim3(1, 4, HEADS), 256, 0, stream>>>(zin, AV, Wb, DH);

    // 6) rows: attn1 @ W + depthwise residual conv -> out_buf (npad x 512)
    outrows_k<<<dim3(NPAD, HEADS), 256, 0, stream>>>(Q, KL, Wb, V, convw, OB);

    // 7) enc = (out_buf @ w_out + b_out)[last 10000] + bag
    sgemm_k<1><<<dim3(DMODEL / 64, (NSEQ + 63) / 64), 256, 0, stream>>>(
        OB + (size_t)PADR * DMODEL, w_out, NSEQ, DMODEL, DMODEL, 0,
        ENC, b_out, bag, nullptr, nullptr, nullptr, nullptr);

    // 8) qe = enc @ wq, ke = enc @ wk
    sgemm_k<2><<<dim3(DQK / 64, (NSEQ + 63) / 64), 256, 0, stream>>>(
        ENC, wq, NSEQ, DQK, DMODEL, 0, QE, nullptr, nullptr, nullptr, nullptr, nullptr, nullptr);
    sgemm_k<2><<<dim3(DQK / 64, (NSEQ + 63) / 64), 256, 0, stream>>>(
        ENC, wk, NSEQ, DQK, DMODEL, 0, KE, nullptr, nullptr, nullptr, nullptr, nullptr, nullptr);

    // 9) sparse edge scores -> A_raw (d_out[1..10000])
    edges_k<<<(E * 64 + 255) / 256, 256, 0, stream>>>(arow, acol, aval, QE, KE, out + 1, E);

    // 10) alpha = softmax(A_raw)
    alphasm_k<<<1, 1024, 0, stream>>>(out + 1, ALPHA);

    // 11) value = bag @ wv_w + wv_b ; xo epilogue (uses alpha, enc)
    sgemm_k<3><<<dim3(DMODEL / 64, (NSEQ + 63) / 64), 256, 0, stream>>>(
        bag, wv_w, NSEQ, DMODEL, DMODEL, 0, XO, wv_b, ENC, ALPHA, nullptr, nullptr, nullptr);

    // 12) out[0] = fc_bias + sum_i xo[i] . fc
    pooled_k<<<160, 256, 0, stream>>>(XO, fck, out);
}

// Round 3
// 1049.225 us; speedup vs baseline: 2.8074x; 2.8074x over previous
//
#include <hip/hip_runtime.h>
#include <hip/hip_bf16.h>
#include <math.h>

#define NSEQ   10000
#define NPAD   10240
#define PADR   240
#define HEADS  8
#define DH     64
#define LM     256
#define LFAC   40
#define DMODEL 512
#define DQK    256
#define OUTSZ  20001

typedef __attribute__((ext_vector_type(8))) short bf16x8;
typedef __attribute__((ext_vector_type(4))) float f32x4;
#define MFMA16(a,b,c) __builtin_amdgcn_mfma_f32_16x16x32_bf16(a,b,c,0,0,0)

__device__ __forceinline__ float b2f(ushort u) {
    return __uint_as_float(((unsigned)u) << 16);
}
__device__ __forceinline__ ushort f2b(float f) {
    unsigned u = __float_as_uint(f);
    unsigned r = (u + 0x7FFFu + ((u >> 16) & 1u)) >> 16;
    return (ushort)r;
}

// ---------------------------------------------------------------- converts
__global__ __launch_bounds__(256) void cvt_k(const float* __restrict__ in,
                                             ushort* __restrict__ out, int n4)
{
    int i = blockIdx.x * 256 + threadIdx.x;
    if (i < n4) {
        float4 v = ((const float4*)in)[i];
        ushort4 u; u.x = f2b(v.x); u.y = f2b(v.y); u.z = f2b(v.z); u.w = f2b(v.w);
        ((ushort4*)out)[i] = u;
    }
}

// transpose+convert: in[R][C] fp32 -> out[C][R] bf16 (R,C multiples of 32)
__global__ __launch_bounds__(256) void tcvt_k(const float* __restrict__ in,
                                              ushort* __restrict__ out, int R, int C)
{
    __shared__ float tile[32][33];
    int c0 = blockIdx.x * 32, r0 = blockIdx.y * 32;
    int tx = threadIdx.x & 31, ty = threadIdx.x >> 5;
    for (int i = ty; i < 32; i += 8) tile[i][tx] = in[(size_t)(r0 + i) * C + c0 + tx];
    __syncthreads();
    for (int i = ty; i < 32; i += 8) out[(size_t)(c0 + i) * R + r0 + tx] = f2b(tile[tx][i]);
}

// ---------------------------------------------------------------- MFMA GEMM
// C = A(Mlog x K, bf16, row-major, padr virtual zero rows) @ B (Bt = B^T,
// bf16 row-major [N][K]).  Tiles BM x BM, 4 waves (2x2), BK=32.
//  MODE 0: QKV split -> P0/P1/P2 bf16 [h][NPAD][64], q scaled 0.125
//  MODE 1: o = v + bias[c] + extra[r][c] -> P0 fp32, P1 bf16
//  MODE 2: P0 fp32 = v
//  MODE 3: xo epilogue (alpha, bias, extra=ENCf) -> P0 fp32
//  MODE 4: P0 bf16 plain (*scale), P1 bf16 transposed (*scale)   [batched]
//  MODE 5: P1 bf16 transposed only (*scale)                      [batched]
//  BCI: stage B as (cval*I - X) from Xt source (pinv fusion)
template<int BM, int MODE, bool BCI>
__global__ __launch_bounds__(256)
void mgemm(const ushort* __restrict__ A, const ushort* __restrict__ Bt,
           int Mlog, int N, int K, int padr,
           long sA, long sB, long sC,
           float cval, float scale,
           void* __restrict__ P0, void* __restrict__ P1, void* __restrict__ P2,
           const float* __restrict__ bias, const float* __restrict__ extra,
           const float* __restrict__ alpha)
{
    constexpr int MF = BM / 32;           // frags per wave per dim
    __shared__ ushort As[BM * 40];
    __shared__ ushort Bs[BM * 40];
    const int tid = threadIdx.x;
    const int l = tid & 63, w = tid >> 6;
    const int wm = w >> 1, wn = w & 1;
    const int row0 = blockIdx.y * BM, col0 = blockIdx.x * BM;
    const int h = blockIdx.z;
    const ushort* Ab = A + (size_t)h * sA;
    const ushort* Btb = Bt + (size_t)h * sB;
    const int lr = l & 15, lk = (l >> 4) * 8;
    f32x4 acc[MF][MF];
    #pragma unroll
    for (int i = 0; i < MF; ++i)
        #pragma unroll
        for (int j = 0; j < MF; ++j) acc[i][j] = (f32x4){0.f, 0.f, 0.f, 0.f};

    for (int k0 = 0; k0 < K; k0 += 32) {
        if (BM == 128) {
            int row = tid >> 1, half = (tid & 1) * 16;
            {   // A tile
                int phys = row0 + row - padr;
                uint4 v0 = {0,0,0,0}, v1 = {0,0,0,0};
                if (phys >= 0 && phys < Mlog - padr) {
                    const uint4* src = (const uint4*)(Ab + (size_t)phys * K + k0 + half);
                    v0 = src[0]; v1 = src[1];
                }
                *(uint4*)&As[row * 40 + half] = v0;
                *(uint4*)&As[row * 40 + half + 8] = v1;
            }
            {   // B tile
                const uint4* src = (const uint4*)(Btb + (size_t)(col0 + row) * K + k0 + half);
                uint4 v0 = src[0], v1 = src[1];
                if (BCI) {
                    union { uint4 u; ushort s[8]; } t0, t1; t0.u = v0; t1.u = v1;
                    int gn = col0 + row;
                    #pragma unroll
                    for (int e = 0; e < 8; ++e) {
                        int gk0 = k0 + half + e, gk1 = gk0 + 8;
                        t0.s[e] = f2b(((gn == gk0) ? cval : 0.f) - b2f(t0.s[e]));
                        t1.s[e] = f2b(((gn == gk1) ? cval : 0.f) - b2f(t1.s[e]));
                    }
                    v0 = t0.u; v1 = t1.u;
                }
                *(uint4*)&Bs[row * 40 + half] = v0;
                *(uint4*)&Bs[row * 40 + half + 8] = v1;
            }
        } else {  // BM == 64
            int row = tid >> 2, q8 = (tid & 3) * 8;
            {
                int phys = row0 + row - padr;
                uint4 v = {0,0,0,0};
                if (phys >= 0 && phys < Mlog - padr)
                    v = *(const uint4*)(Ab + (size_t)phys * K + k0 + q8);
                *(uint4*)&As[row * 40 + q8] = v;
            }
            {
                uint4 v = *(const uint4*)(Btb + (size_t)(col0 + row) * K + k0 + q8);
                if (BCI) {
                    union { uint4 u; ushort s[8]; } t; t.u = v;
                    int gn = col0 + row;
                    #pragma unroll
                    for (int e = 0; e < 8; ++e) {
                        int gk = k0 + q8 + e;
                        t.s[e] = f2b(((gn == gk) ? cval : 0.f) - b2f(t.s[e]));
                    }
                    v = t.u;
                }
                *(uint4*)&Bs[row * 40 + q8] = v;
            }
        }
        __syncthreads();
        bf16x8 af[MF];
        #pragma unroll
        for (int mf = 0; mf < MF; ++mf)
            af[mf] = *(const bf16x8*)&As[(wm * (BM / 2) + mf * 16 + lr) * 40 + lk];
        #pragma unroll
        for (int nf = 0; nf < MF; ++nf) {
            bf16x8 bfr = *(const bf16x8*)&Bs[(wn * (BM / 2) + nf * 16 + lr) * 40 + lk];
            #pragma unroll
            for (int mf = 0; mf < MF; ++mf)
                acc[mf][nf] = MFMA16(af[mf], bfr, acc[mf][nf]);
        }
        __syncthreads();
    }

    const int Wr = BM / 2;
    #pragma unroll
    for (int mf = 0; mf < MF; ++mf)
    #pragma unroll
    for (int nf = 0; nf < MF; ++nf) {
        if (MODE != 5) {
            #pragma unroll
            for (int i = 0; i < 4; ++i) {
                int r = row0 + wm * Wr + mf * 16 + (l >> 4) * 4 + i;
                int c = col0 + wn * Wr + nf * 16 + lr;
                float v = acc[mf][nf][i];
                if (MODE == 0) {
                    int t = c >> 9, hh = (c >> 6) & 7, d = c & 63;
                    ushort* dst = (t == 0) ? (ushort*)P0 : (t == 1) ? (ushort*)P1 : (ushort*)P2;
                    dst[((size_t)hh * NPAD + r) * DH + d] = f2b(t == 0 ? v * 0.125f : v);
                } else if (MODE == 1) {
                    if (r < Mlog) {
                        float o = v + bias[c] + extra[(size_t)r * N + c];
                        ((float*)P0)[(size_t)r * N + c] = o;
                        ((ushort*)P1)[(size_t)r * N + c] = f2b(o);
                    }
                } else if (MODE == 2) {
                    if (r < Mlog) ((float*)P0)[(size_t)r * N + c] = v;
                } else if (MODE == 3) {
                    if (r < Mlog) {
                        float xl = alpha[r] * (v + bias[c]);
                        float s = 1.f / (1.f + __expf(xl));
                        float w2 = s * s;
                        ((float*)P0)[(size_t)r * N + c] =
                            2.f * xl * w2 + 2.f * extra[(size_t)r * N + c] * (1.f - w2);
                    }
                } else if (MODE == 4) {
                    ((ushort*)P0)[(size_t)h * sC + (size_t)r * N + c] = f2b(v * scale);
                }
            }
        }
        if (MODE == 4 || MODE == 5) {
            int r0v = row0 + wm * Wr + mf * 16 + (l >> 4) * 4;
            int c = col0 + wn * Wr + nf * 16 + lr;
            ushort4 pk;
            pk.x = f2b(acc[mf][nf][0] * scale); pk.y = f2b(acc[mf][nf][1] * scale);
            pk.z = f2b(acc[mf][nf][2] * scale); pk.w = f2b(acc[mf][nf][3] * scale);
            *(ushort4*)&((ushort*)P1)[(size_t)h * sC + (size_t)c * Mlog + r0v] = pk;
        }
    }
}

// ---------------------------------------------------------------- landmarks
__global__ void landmark_k(const ushort* __restrict__ src, ushort* __restrict__ dst)
{
    int b = blockIdx.x;
    int hh = b >> 8, j = b & 255, d = threadIdx.x;
    const ushort* p = src + ((size_t)hh * NPAD + (size_t)j * LFAC) * DH + d;
    float s = 0.f;
    #pragma unroll
    for (int t = 0; t < LFAC; ++t) s += b2f(p[t * DH]);
    dst[((size_t)hh * LM + j) * DH + d] = f2b(s * (1.f / LFAC));
}

// attn2 = softmax(q_l @ k_l^T)
__global__ __launch_bounds__(256)
void attn2_k(const ushort* __restrict__ QL, const ushort* __restrict__ KL,
             ushort* __restrict__ X2b)
{
    int i = blockIdx.x, h = blockIdx.y, j = threadIdx.x;
    __shared__ float qv[DH];
    __shared__ float red[256];
    if (j < DH) qv[j] = b2f(QL[((size_t)h * LM + i) * DH + j]);
    __syncthreads();
    const ushort* kp = KL + ((size_t)h * LM + j) * DH;
    float dot = 0.f;
    #pragma unroll
    for (int d = 0; d < DH; ++d) dot += qv[d] * b2f(kp[d]);
    red[j] = dot; __syncthreads();
    for (int s = 128; s > 0; s >>= 1) { if (j < s) red[j] = fmaxf(red[j], red[j + s]); __syncthreads(); }
    float mx = red[0]; __syncthreads();
    float e = __expf(dot - mx);
    red[j] = e; __syncthreads();
    for (int s = 128; s > 0; s >>= 1) { if (j < s) red[j] += red[j + s]; __syncthreads(); }
    X2b[((size_t)h * LM + i) * LM + j] = f2b(e / red[0]);
}

__global__ __launch_bounds__(256)
void colrow_k(const ushort* __restrict__ X2b, unsigned int* __restrict__ mx)
{
    int h = blockIdx.x, t = threadIdx.x;
    const ushort* x = X2b + (size_t)h * LM * LM;
    float cs = 0.f, rs = 0.f;
    for (int j = 0; j < LM; ++j) cs += fabsf(b2f(x[(size_t)t * LM + j]));
    for (int i = 0; i < LM; ++i) rs += fabsf(b2f(x[(size_t)i * LM + t]));
    __shared__ float r1[256], r2[256];
    r1[t] = cs; r2[t] = rs; __syncthreads();
    for (int s = 128; s > 0; s >>= 1) {
        if (t < s) { r1[t] = fmaxf(r1[t], r1[t + s]); r2[t] = fmaxf(r2[t], r2[t + s]); }
        __syncthreads();
    }
    if (t == 0) {
        atomicMax(&mx[0], __float_as_uint(r1[0]));
        atomicMax(&mx[1], __float_as_uint(r2[0]));
    }
}

__global__ void zinit_k(const ushort* __restrict__ X2b, const float* __restrict__ mxf,
                        ushort* __restrict__ Z, ushort* __restrict__ Zt)
{
    int i = blockIdx.x, h = blockIdx.y, j = threadIdx.x;
    float scale = 1.f / (mxf[0] * mxf[1]);
    float x = b2f(X2b[((size_t)h * LM + i) * LM + j]) * scale;
    ushort u = f2b(x);
    Z[((size_t)h * LM + j) * LM + i] = u;
    Zt[((size_t)h * LM + i) * LM + j] = u;
}

// AVt[h][d][i] = (softmax_j(q_l[h][i].k[h][j]) @ v)[d]
__global__ __launch_bounds__(256)
void attn3v_k(const ushort* __restrict__ QL, const ushort* __restrict__ Kb,
              const ushort* __restrict__ Vb, ushort* __restrict__ AVt)
{
    int i = blockIdx.x, h = blockIdx.y, t = threadIdx.x;
    __shared__ float q[DH];
    __shared__ float red[256];
    __shared__ float pbuf[NPAD];
    if (t < DH) q[t] = b2f(QL[((size_t)h * LM + i) * DH + t]);
    __syncthreads();
    float lmax = -INFINITY;
    for (int j = t; j < NPAD; j += 256) {
        const uint4* kp = (const uint4*)(Kb + ((size_t)h * NPAD + j) * DH);
        float dot = 0.f;
        #pragma unroll
        for (int cc = 0; cc < 8; ++cc) {
            union { uint4 u; ushort s[8]; } uu; uu.u = kp[cc];
            #pragma unroll
            for (int e = 0; e < 8; ++e) dot += q[cc * 8 + e] * b2f(uu.s[e]);
        }
        pbuf[j] = dot;
        lmax = fmaxf(lmax, dot);
    }
    red[t] = lmax; __syncthreads();
    for (int s = 128; s > 0; s >>= 1) { if (t < s) red[t] = fmaxf(red[t], red[t + s]); __syncthreads(); }
    float mx = red[0]; __syncthreads();
    float lsum = 0.f;
    for (int j = t; j < NPAD; j += 256) { float e = __expf(pbuf[j] - mx); pbuf[j] = e; lsum += e; }
    red[t] = lsum; __syncthreads();
    for (int s = 128; s > 0; s >>= 1) { if (t < s) red[t] += red[t + s]; __syncthreads(); }
    float inv = 1.f / red[0];
    __syncthreads();
    int d = t & 63, c = t >> 6;
    float acc = 0.f;
    for (int j = c * (NPAD / 4); j < (c + 1) * (NPAD / 4); ++j)
        acc += pbuf[j] * b2f(Vb[((size_t)h * NPAD + j) * DH + d]);
    red[t] = acc; __syncthreads();
    if (c == 0)
        AVt[((size_t)h * DH + d) * LM + i] =
            f2b((red[d] + red[d + 64] + red[d + 128] + red[d + 192]) * inv);
}

// depthwise conv residual -> OBf fp32 [10000][512]
__global__ __launch_bounds__(256)
void conv_k(const ushort* __restrict__ Vb, const float* __restrict__ cw,
            float* __restrict__ OBf)
{
    int idx = blockIdx.x * 256 + threadIdx.x;
    if (idx >= NSEQ * 128) return;
    int ro = idx >> 7, c4 = idx & 127;
    int h = c4 >> 4, dq = (c4 & 15) * 4;
    int i = ro + PADR;
    float a0 = 0, a1 = 0, a2 = 0, a3 = 0;
    #pragma unroll
    for (int tt = 0; tt < 33; ++tt) {
        int src = i + tt - 16;
        if (src < NPAD) {
            float wv = cw[h * 33 + tt];
            ushort4 u = *(const ushort4*)(Vb + ((size_t)h * NPAD + src) * DH + dq);
            a0 += wv * b2f(u.x); a1 += wv * b2f(u.y);
            a2 += wv * b2f(u.z); a3 += wv * b2f(u.w);
        }
    }
    *(float4*)&OBf[(size_t)ro * DMODEL + h * DH + dq] = make_float4(a0, a1, a2, a3);
}

// fused attn1 @ W + conv residual -> OBb bf16 [10000][512]
__global__ __launch_bounds__(256, 2)
void outrows_mfma(const ushort* __restrict__ Qb, const ushort* __restrict__ KLb,
                  const ushort* __restrict__ WTg, const float* __restrict__ OBf,
                  ushort* __restrict__ OBb)
{
    __shared__ __align__(16) char smem[65536];
    ushort* Qs = (ushort*)smem;                    // [128][72]
    ushort* KLs = (ushort*)(smem + 128 * 72 * 2);  // [256][72]
    ushort* Ps = (ushort*)smem;                    // [128][256] swizzled (phase 2)
    const int tid = threadIdx.x, l = tid & 63, w = tid >> 6;
    const int h = blockIdx.y, i0 = blockIdx.x * 128;
    const int lr = l & 15, lg = l >> 4;
    {   // Q tile: 128 rows x 64 cols, 32 ushorts (4 x uint4) per thread
        int row = tid >> 1, half = (tid & 1) * 32;
        const uint4* src = (const uint4*)(Qb + ((size_t)h * NPAD + i0 + row) * DH + half);
        uint4 a = src[0], b = src[1], c = src[2], d = src[3];
        *(uint4*)&Qs[row * 72 + half] = a;
        *(uint4*)&Qs[row * 72 + half + 8] = b;
        *(uint4*)&Qs[row * 72 + half + 16] = c;
        *(uint4*)&Qs[row * 72 + half + 24] = d;
    }
    {   // KL tile: 256 rows x 64 cols, one full row (8 x uint4) per thread
        int row = tid;
        const uint4* src = (const uint4*)(KLb + ((size_t)h * LM + row) * DH);
        #pragma unroll
        for (int e = 0; e < 8; ++e) {
            uint4 v = src[e];
            *(uint4*)&KLs[row * 72 + e * 8] = v;
        }
    }
    __syncthreads();
    f32x4 s[2][16];
    #pragma unroll
    for (int mf = 0; mf < 2; ++mf)
        #pragma unroll
        for (int nf = 0; nf < 16; ++nf) s[mf][nf] = (f32x4){0.f, 0.f, 0.f, 0.f};
    #pragma unroll
    for (int ks = 0; ks < 2; ++ks) {
        bf16x8 a0 = *(const bf16x8*)&Qs[(w * 32 + 0 + lr) * 72 + ks * 32 + lg * 8];
        bf16x8 a1 = *(const bf16x8*)&Qs[(w * 32 + 16 + lr) * 72 + ks * 32 + lg * 8];
        #pragma unroll
        for (int nf = 0; nf < 16; ++nf) {
            bf16x8 b = *(const bf16x8*)&KLs[(nf * 16 + lr) * 72 + ks * 32 + lg * 8];
            s[0][nf] = MFMA16(a0, b, s[0][nf]);
            s[1][nf] = MFMA16(a1, b, s[1][nf]);
        }
    }
    float inv_[2][4];
    #pragma unroll
    for (int mf = 0; mf < 2; ++mf)
    #pragma unroll
    for (int i = 0; i < 4; ++i) {
        float m = s[mf][0][i];
        #pragma unroll
        for (int nf = 1; nf < 16; ++nf) m = fmaxf(m, s[mf][nf][i]);
        m = fmaxf(m, __shfl_xor(m, 1)); m = fmaxf(m, __shfl_xor(m, 2));
        m = fmaxf(m, __shfl_xor(m, 4)); m = fmaxf(m, __shfl_xor(m, 8));
        float sum = 0.f;
        #pragma unroll
        for (int nf = 0; nf < 16; ++nf) {
            float e = __expf(s[mf][nf][i] - m); s[mf][nf][i] = e; sum += e;
        }
        sum += __shfl_xor(sum, 1); sum += __shfl_xor(sum, 2);
        sum += __shfl_xor(sum, 4); sum += __shfl_xor(sum, 8);
        inv_[mf][i] = 1.f / sum;
    }
    __syncthreads();
    #pragma unroll
    for (int mf = 0; mf < 2; ++mf)
    #pragma unroll
    for (int nf = 0; nf < 16; ++nf)
    #pragma unroll
    for (int i = 0; i < 4; ++i) {
        int row = w * 32 + mf * 16 + lg * 4 + i;
        int col = nf * 16 + lr;
        Ps[row * 256 + (col ^ ((row & 7) << 3))] = f2b(s[mf][nf][i] * inv_[mf][i]);
    }
    __syncthreads();
    const int wm = w >> 1, wn = w & 1;
    f32x4 o[4][2];
    #pragma unroll
    for (int mf = 0; mf < 4; ++mf)
        #pragma unroll
        for (int nf = 0; nf < 2; ++nf) o[mf][nf] = (f32x4){0.f, 0.f, 0.f, 0.f};
    #pragma unroll
    for (int ks = 0; ks < 8; ++ks) {
        bf16x8 a[4];
        #pragma unroll
        for (int mf = 0; mf < 4; ++mf) {
            int row = wm * 64 + mf * 16 + lr;
            int kcol = ks * 32 + lg * 8;
            a[mf] = *(const bf16x8*)&Ps[row * 256 + (kcol ^ ((row & 7) << 3))];
        }
        #pragma unroll
        for (int nf = 0; nf < 2; ++nf) {
            int d = wn * 32 + nf * 16 + lr;
            bf16x8 b = *(const bf16x8*)(WTg + ((size_t)h * DH + d) * LM + ks * 32 + lg * 8);
            #pragma unroll
            for (int mf = 0; mf < 4; ++mf) o[mf][nf] = MFMA16(a[mf], b, o[mf][nf]);
        }
    }
    #pragma unroll
    for (int mf = 0; mf < 4; ++mf)
    #pragma unroll
    for (int nf = 0; nf < 2; ++nf)
    #pragma unroll
    for (int i = 0; i < 4; ++i) {
        int r = i0 + wm * 64 + mf * 16 + lg * 4 + i;
        if (r >= PADR) {
            int ro = r - PADR;
            int c = h * DH + wn * 32 + nf * 16 + lr;
            float v = o[mf][nf][i] + OBf[(size_t)ro * DMODEL + c];
            OBb[(size_t)ro * DMODEL + c] = f2b(v);
        }
    }
}

// ---------------------------------------------------------------- tail ops
__global__ __launch_bounds__(256)
void edges_k(const int* __restrict__ rows, const int* __restrict__ cols,
             const float* __restrict__ vals,
             const float* __restrict__ QE, const float* __restrict__ KE,
             float* __restrict__ A_raw, int E)
{
    int gid = blockIdx.x * blockDim.x + threadIdx.x;
    int e = gid >> 6, l = gid & 63;
    if (e >= E) return;
    int r = rows[e], c = cols[e];
    const float* qp = QE + (size_t)r * DQK;
    const float* kp = KE + (size_t)c * DQK;
    float dot = 0.f;
    #pragma unroll
    for (int d = l; d < DQK; d += 64) dot += qp[d] * kp[d];
    #pragma unroll
    for (int s = 32; s > 0; s >>= 1) dot += __shfl_down(dot, s);
    if (l == 0) atomicAdd(&A_raw[r], vals[e] * dot * 0.0625f);
}

__global__ __launch_bounds__(1024)
void alphasm_k(const float* __restrict__ A_raw, float* __restrict__ alpha)
{
    __shared__ float red[1024];
    int t = threadIdx.x;
    float lm = -INFINITY;
    for (int i = t; i < NSEQ; i += 1024) lm = fmaxf(lm, A_raw[i]);
    red[t] = lm; __syncthreads();
    for (int s = 512; s > 0; s >>= 1) { if (t < s) red[t] = fmaxf(red[t], red[t + s]); __syncthreads(); }
    float mx = red[0]; __syncthreads();
    float ls = 0.f;
    for (int i = t; i < NSEQ; i += 1024) ls += __expf(A_raw[i] - mx);
    red[t] = ls; __syncthreads();
    for (int s = 512; s > 0; s >>= 1) { if (t < s) red[t] += red[t + s]; __syncthreads(); }
    float inv = 1.f / red[0];
    for (int i = t; i < NSEQ; i += 1024) alpha[i] = __expf(A_raw[i] - mx) * inv;
}

__global__ void init_k(float* __restrict__ out, const float* __restrict__ fcb,
                       unsigned int* __restrict__ mx)
{
    int t = blockIdx.x * blockDim.x + threadIdx.x;
    if (t == 0) { out[0] = fcb[0]; mx[0] = 0u; mx[1] = 0u; }
    if (t >= 1 && t <= NSEQ) out[t] = 0.f;
    if (t >= NSEQ + 1 && t < OUTSZ) out[t] = 1.0f;
}

__global__ __launch_bounds__(256)
void pooled_k(const float* __restrict__ XO, const float* __restrict__ fc,
              float* __restrict__ out0)
{
    __shared__ float red[256];
    int t = threadIdx.x;
    float acc = 0.f;
    const size_t total = (size_t)NSEQ * DMODEL;
    for (size_t idx = (size_t)blockIdx.x * 256 + t; idx < total; idx += (size_t)gridDim.x * 256) {
        int d = (int)(idx & (DMODEL - 1));
        acc += XO[idx] * fc[d];
    }
    red[t] = acc; __syncthreads();
    for (int s = 128; s > 0; s >>= 1) { if (t < s) red[t] += red[t + s]; __syncthreads(); }
    if (t == 0) atomicAdd(out0, red[0]);
}

// ---------------------------------------------------------------- launch
extern "C" void kernel_launch(void* const* d_in, const int* in_sizes, int n_in,
                              void* d_out, int out_size, void* d_ws, size_t ws_size,
                              hipStream_t stream)
{
    (void)n_in; (void)out_size; (void)ws_size;
    const float* bag   = (const float*)d_in[0];
    const int*   arow  = (const int*)d_in[1];
    const int*   acol  = (const int*)d_in[2];
    const float* aval  = (const float*)d_in[3];
    const float* w_qkv = (const float*)d_in[4];
    const float* w_out = (const float*)d_in[5];
    const float* b_out = (const float*)d_in[6];
    const float* convw = (const float*)d_in[7];
    const float* wq    = (const float*)d_in[8];
    const float* wk    = (const float*)d_in[9];
    const float* wv_w  = (const float*)d_in[10];
    const float* wv_b  = (const float*)d_in[11];
    const float* fck   = (const float*)d_in[15];
    const float* fcb   = (const float*)d_in[16];
    const int E = in_sizes[1];
    float* out = (float*)d_out;

    char* ws = (char*)d_ws;
    size_t off = 0;
    auto alloc = [&](size_t bytes) { void* p = ws + off; off += (bytes + 255) & ~(size_t)255; return p; };
    ushort* Qb    = (ushort*)alloc((size_t)HEADS * NPAD * DH * 2);
    ushort* Kb    = (ushort*)alloc((size_t)HEADS * NPAD * DH * 2);
    ushort* Vb    = (ushort*)alloc((size_t)HEADS * NPAD * DH * 2);
    ushort* bagb  = (ushort*)alloc((size_t)NSEQ * DMODEL * 2);
    ushort* wqkvT = (ushort*)alloc((size_t)1536 * 512 * 2);
    ushort* woutT = (ushort*)alloc((size_t)512 * 512 * 2);
    ushort* wqT   = (ushort*)alloc((size_t)256 * 512 * 2);
    ushort* wkT   = (ushort*)alloc((size_t)256 * 512 * 2);
    ushort* wvwT  = (ushort*)alloc((size_t)512 * 512 * 2);
    ushort* QLb   = (ushort*)alloc((size_t)HEADS * LM * DH * 2);
    ushort* KLb   = (ushort*)alloc((size_t)HEADS * LM * DH * 2);
    ushort* X2b   = (ushort*)alloc((size_t)HEADS * LM * LM * 2);
    ushort* Za    = (ushort*)alloc((size_t)HEADS * LM * LM * 2);
    ushort* Zat   = (ushort*)alloc((size_t)HEADS * LM * LM * 2);
    ushort* Zb2   = (ushort*)alloc((size_t)HEADS * LM * LM * 2);
    ushort* Zbt2  = (ushort*)alloc((size_t)HEADS * LM * LM * 2);
    ushort* T0    = (ushort*)alloc((size_t)HEADS * LM * LM * 2);
    ushort* T0t   = (ushort*)alloc((size_t)HEADS * LM * LM * 2);
    ushort* T1t   = (ushort*)alloc((size_t)HEADS * LM * LM * 2);
    ushort* T2t   = (ushort*)alloc((size_t)HEADS * LM * LM * 2);
    ushort* AVt   = (ushort*)alloc((size_t)HEADS * DH * LM * 2);
    ushort* WT    = (ushort*)alloc((size_t)HEADS * DH * LM * 2);
    float*  OBf   = (float*)alloc((size_t)NSEQ * DMODEL * 4);
    ushort* OBb   = (ushort*)alloc((size_t)NSEQ * DMODEL * 2);
    float*  ENCf  = (float*)alloc((size_t)NSEQ * DMODEL * 4);
    ushort* ENCb  = (ushort*)alloc((size_t)NSEQ * DMODEL * 2);
    float*  ALPHA = (float*)alloc((size_t)NPAD * 4);
    float*  MXf   = (float*)alloc(256);
    unsigned int* MX = (unsigned int*)MXf;
    // aliases (disjoint lifetimes)
    float* QE = (float*)Qb;   // 10000x256 fp32 (Qb dead after outrows)
    float* KE = (float*)Kb;   // (Kb dead after attn3v)
    float* XO = OBf;          // (OBf dead after outrows)

    const long ZS = (long)LM * LM;      // 65536
    const long WS = (long)DH * LM;      // 16384

    init_k<<<(OUTSZ + 255) / 256, 256, 0, stream>>>(out, fcb, MX);

    // converts / transposes
    cvt_k<<<(NSEQ * DMODEL / 4 + 255) / 256, 256, 0, stream>>>(bag, bagb, NSEQ * DMODEL / 4);
    tcvt_k<<<dim3(1536 / 32, 512 / 32), 256, 0, stream>>>(w_qkv, wqkvT, 512, 1536);
    tcvt_k<<<dim3(512 / 32, 512 / 32), 256, 0, stream>>>(w_out, woutT, 512, 512);
    tcvt_k<<<dim3(256 / 32, 512 / 32), 256, 0, stream>>>(wq, wqT, 512, 256);
    tcvt_k<<<dim3(256 / 32, 512 / 32), 256, 0, stream>>>(wk, wkT, 512, 256);
    tcvt_k<<<dim3(512 / 32, 512 / 32), 256, 0, stream>>>(wv_w, wvwT, 512, 512);

    // QKV projection
    mgemm<128, 0, false><<<dim3(12, 80, 1), 256, 0, stream>>>(
        bagb, wqkvT, NPAD, 1536, 512, PADR, 0, 0, 0, 0.f, 1.f,
        Qb, Kb, Vb, nullptr, nullptr, nullptr);

    landmark_k<<<HEADS * LM, DH, 0, stream>>>(Qb, QLb);
    landmark_k<<<HEADS * LM, DH, 0, stream>>>(Kb, KLb);

    attn2_k<<<dim3(LM, HEADS), 256, 0, stream>>>(QLb, KLb, X2b);
    colrow_k<<<HEADS, 256, 0, stream>>>(X2b, MX);
    zinit_k<<<dim3(LM, HEADS), 256, 0, stream>>>(X2b, MXf, Za, Zat);

    // Newton-Schulz pinv (imsub fused into B staging)
    ushort *Z = Za, *Zt = Zat, *Zn = Zb2, *Znt = Zbt2;
    for (int it = 0; it < 6; ++it) {
        mgemm<64, 4, false><<<dim3(4, 4, HEADS), 256, 0, stream>>>(
            X2b, Zt, LM, LM, LM, 0, ZS, ZS, ZS, 0.f, 1.f,
            T0, T0t, nullptr, nullptr, nullptr, nullptr);
        mgemm<64, 5, true><<<dim3(4, 4, HEADS), 256, 0, stream>>>(
            T0, T0t, LM, LM, LM, 0, ZS, ZS, ZS, 7.f, 1.f,
            nullptr, T1t, nullptr, nullptr, nullptr, nullptr);
        mgemm<64, 5, true><<<dim3(4, 4, HEADS), 256, 0, stream>>>(
            T0, T1t, LM, LM, LM, 0, ZS, ZS, ZS, 15.f, 1.f,
            nullptr, T2t, nullptr, nullptr, nullptr, nullptr);
        mgemm<64, 4, true><<<dim3(4, 4, HEADS), 256, 0, stream>>>(
            Z, T2t, LM, LM, LM, 0, ZS, ZS, ZS, 13.f, 0.25f,
            Zn, Znt, nullptr, nullptr, nullptr, nullptr);
        ushort* t;
        t = Z; Z = Zn; Zn = t;
        t = Zt; Zt = Znt; Znt = t;
    }

    // attn3 @ v, then W^T = (Z @ AV)^T
    attn3v_k<<<dim3(LM, HEADS), 256, 0, stream>>>(QLb, Kb, Vb, AVt);
    mgemm<64, 5, false><<<dim3(1, 4, HEADS), 256, 0, stream>>>(
        Z, AVt, LM, DH, LM, 0, ZS, WS, WS, 0.f, 1.f,
        nullptr, WT, nullptr, nullptr, nullptr, nullptr);

    // conv residual, then fused attn1 @ W + residual
    conv_k<<<(NSEQ * 128 + 255) / 256, 256, 0, stream>>>(Vb, convw, OBf);
    outrows_mfma<<<dim3(NPAD / 128, HEADS), 256, 0, stream>>>(Qb, KLb, WT, OBf, OBb);

    // enc = out_buf @ w_out + b_out + bag
    mgemm<128, 1, false><<<dim3(4, 79), 256, 0, stream>>>(
        OBb, woutT, NSEQ, DMODEL, 512, 0, 0, 0, 0, 0.f, 1.f,
        ENCf, ENCb, nullptr, b_out, bag, nullptr);

    // qe / ke
    mgemm<128, 2, false><<<dim3(2, 79), 256, 0, stream>>>(
        ENCb, wqT, NSEQ, DQK, 512, 0, 0, 0, 0, 0.f, 1.f,
        QE, nullptr, nullptr, nullptr, nullptr, nullptr);
    mgemm<128, 2, false><<<dim3(2, 79), 256, 0, stream>>>(
        ENCb, wkT, NSEQ, DQK, 512, 0, 0, 0, 0, 0.f, 1.f,
        KE, nullptr, nullptr, nullptr, nullptr, nullptr);

    // sparse edges -> A_raw, softmax -> alpha
    edges_k<<<(E * 64 + 255) / 256, 256, 0, stream>>>(arow, acol, aval, QE, KE, out + 1, E);
    alphasm_k<<<1, 1024, 0, stream>>>(out + 1, ALPHA);

    // value + xo epilogue
    mgemm<128, 3, false><<<dim3(4, 79), 256, 0, stream>>>(
        bagb, wvwT, NSEQ, DMODEL, 512, 0, 0, 0, 0, 0.f, 1.f,
        XO, nullptr, nullptr, wv_b, ENCf, ALPHA);

    pooled_k<<<160, 256, 0, stream>>>(XO, fck, out);
}

// Round 4
// 548.767 us; speedup vs baseline: 5.3676x; 1.9120x over previous
//
#include <hip/hip_runtime.h>
#include <hip/hip_bf16.h>
#include <math.h>

#define NSEQ   10000
#define NPAD   10240
#define PADR   240
#define HEADS  8
#define DH     64
#define LM     256
#define LFAC   40
#define DMODEL 512
#define DQK    256
#define OUTSZ  20001
#define NSPLIT 16
#define KCH    128

typedef __attribute__((ext_vector_type(8))) short bf16x8;
typedef __attribute__((ext_vector_type(4))) float f32x4;
#define MFMA16(a,b,c) __builtin_amdgcn_mfma_f32_16x16x32_bf16(a,b,c,0,0,0)

__device__ __forceinline__ float b2f(ushort u) {
    return __uint_as_float(((unsigned)u) << 16);
}
__device__ __forceinline__ ushort f2b(float f) {
    unsigned u = __float_as_uint(f);
    unsigned r = (u + 0x7FFFu + ((u >> 16) & 1u)) >> 16;
    return (ushort)r;
}

// ---------------------------------------------------------------- converts
__global__ __launch_bounds__(256) void cvt_k(const float* __restrict__ in,
                                             ushort* __restrict__ out, int n4)
{
    int i = blockIdx.x * 256 + threadIdx.x;
    if (i < n4) {
        float4 v = ((const float4*)in)[i];
        ushort4 u; u.x = f2b(v.x); u.y = f2b(v.y); u.z = f2b(v.z); u.w = f2b(v.w);
        ((ushort4*)out)[i] = u;
    }
}

// transpose+convert: in[R][C] fp32 -> out[C][R] bf16 (R,C multiples of 32)
__global__ __launch_bounds__(256) void tcvt_k(const float* __restrict__ in,
                                              ushort* __restrict__ out, int R, int C)
{
    __shared__ float tile[32][33];
    int c0 = blockIdx.x * 32, r0 = blockIdx.y * 32;
    int tx = threadIdx.x & 31, ty = threadIdx.x >> 5;
    for (int i = ty; i < 32; i += 8) tile[i][tx] = in[(size_t)(r0 + i) * C + c0 + tx];
    __syncthreads();
    for (int i = ty; i < 32; i += 8) out[(size_t)(c0 + i) * R + r0 + tx] = f2b(tile[tx][i]);
}

// ---------------------------------------------------------------- MFMA GEMM
//  MODE 0: QKV split -> P0/P1/P2 bf16 [h][NPAD][64], q*0.125; P3 = V^T pack
//  MODE 1: o = v + bias[c] + extra[r][c] -> P0 fp32, P1 bf16
//  MODE 2: P0 fp32 = v
//  MODE 3: xo epilogue (alpha, bias, extra=ENCf) -> P0 fp32
//  MODE 4: P0 bf16 plain (*scale), P1 bf16 transposed (*scale)   [batched]
//  MODE 5: P1 bf16 transposed only (*scale)                      [batched]
//  BCI: stage B as (cval*I - X) (pinv fusion)
template<int BM, int MODE, bool BCI>
__global__ __launch_bounds__(256)
void mgemm(const ushort* __restrict__ A, const ushort* __restrict__ Bt,
           int Mlog, int N, int K, int padr,
           long sA, long sB, long sC,
           float cval, float scale,
           void* __restrict__ P0, void* __restrict__ P1, void* __restrict__ P2,
           void* __restrict__ P3,
           const float* __restrict__ bias, const float* __restrict__ extra,
           const float* __restrict__ alpha)
{
    constexpr int MF = BM / 32;
    __shared__ ushort As[BM * 40];
    __shared__ ushort Bs[BM * 40];
    const int tid = threadIdx.x;
    const int l = tid & 63, w = tid >> 6;
    const int wm = w >> 1, wn = w & 1;
    const int row0 = blockIdx.y * BM, col0 = blockIdx.x * BM;
    const int h = blockIdx.z;
    const ushort* Ab = A + (size_t)h * sA;
    const ushort* Btb = Bt + (size_t)h * sB;
    const int lr = l & 15, lk = (l >> 4) * 8;
    f32x4 acc[MF][MF];
    #pragma unroll
    for (int i = 0; i < MF; ++i)
        #pragma unroll
        for (int j = 0; j < MF; ++j) acc[i][j] = (f32x4){0.f, 0.f, 0.f, 0.f};

    for (int k0 = 0; k0 < K; k0 += 32) {
        if (BM == 128) {
            int row = tid >> 1, half = (tid & 1) * 16;
            {
                int phys = row0 + row - padr;
                uint4 v0 = {0,0,0,0}, v1 = {0,0,0,0};
                if (phys >= 0 && phys < Mlog - padr) {
                    const uint4* src = (const uint4*)(Ab + (size_t)phys * K + k0 + half);
                    v0 = src[0]; v1 = src[1];
                }
                *(uint4*)&As[row * 40 + half] = v0;
                *(uint4*)&As[row * 40 + half + 8] = v1;
            }
            {
                const uint4* src = (const uint4*)(Btb + (size_t)(col0 + row) * K + k0 + half);
                uint4 v0 = src[0], v1 = src[1];
                if (BCI) {
                    union { uint4 u; ushort s[8]; } t0, t1; t0.u = v0; t1.u = v1;
                    int gn = col0 + row;
                    #pragma unroll
                    for (int e = 0; e < 8; ++e) {
                        int gk0 = k0 + half + e, gk1 = gk0 + 8;
                        t0.s[e] = f2b(((gn == gk0) ? cval : 0.f) - b2f(t0.s[e]));
                        t1.s[e] = f2b(((gn == gk1) ? cval : 0.f) - b2f(t1.s[e]));
                    }
                    v0 = t0.u; v1 = t1.u;
                }
                *(uint4*)&Bs[row * 40 + half] = v0;
                *(uint4*)&Bs[row * 40 + half + 8] = v1;
            }
        } else {  // BM == 64
            int row = tid >> 2, q8 = (tid & 3) * 8;
            {
                int phys = row0 + row - padr;
                uint4 v = {0,0,0,0};
                if (phys >= 0 && phys < Mlog - padr)
                    v = *(const uint4*)(Ab + (size_t)phys * K + k0 + q8);
                *(uint4*)&As[row * 40 + q8] = v;
            }
            {
                uint4 v = *(const uint4*)(Btb + (size_t)(col0 + row) * K + k0 + q8);
                if (BCI) {
                    union { uint4 u; ushort s[8]; } t; t.u = v;
                    int gn = col0 + row;
                    #pragma unroll
                    for (int e = 0; e < 8; ++e) {
                        int gk = k0 + q8 + e;
                        t.s[e] = f2b(((gn == gk) ? cval : 0.f) - b2f(t.s[e]));
                    }
                    v = t.u;
                }
                *(uint4*)&Bs[row * 40 + q8] = v;
            }
        }
        __syncthreads();
        bf16x8 af[MF];
        #pragma unroll
        for (int mf = 0; mf < MF; ++mf)
            af[mf] = *(const bf16x8*)&As[(wm * (BM / 2) + mf * 16 + lr) * 40 + lk];
        #pragma unroll
        for (int nf = 0; nf < MF; ++nf) {
            bf16x8 bfr = *(const bf16x8*)&Bs[(wn * (BM / 2) + nf * 16 + lr) * 40 + lk];
            #pragma unroll
            for (int mf = 0; mf < MF; ++mf)
                acc[mf][nf] = MFMA16(af[mf], bfr, acc[mf][nf]);
        }
        __syncthreads();
    }

    const int Wr = BM / 2;
    #pragma unroll
    for (int mf = 0; mf < MF; ++mf)
    #pragma unroll
    for (int nf = 0; nf < MF; ++nf) {
        if (MODE != 5) {
            #pragma unroll
            for (int i = 0; i < 4; ++i) {
                int r = row0 + wm * Wr + mf * 16 + (l >> 4) * 4 + i;
                int c = col0 + wn * Wr + nf * 16 + lr;
                float v = acc[mf][nf][i];
                if (MODE == 0) {
                    int t = c >> 9, hh = (c >> 6) & 7, d = c & 63;
                    ushort* dst = (t == 0) ? (ushort*)P0 : (t == 1) ? (ushort*)P1 : (ushort*)P2;
                    dst[((size_t)hh * NPAD + r) * DH + d] = f2b(t == 0 ? v * 0.125f : v);
                } else if (MODE == 1) {
                    if (r < Mlog) {
                        float o = v + bias[c] + extra[(size_t)r * N + c];
                        ((float*)P0)[(size_t)r * N + c] = o;
                        ((ushort*)P1)[(size_t)r * N + c] = f2b(o);
                    }
                } else if (MODE == 2) {
                    if (r < Mlog) ((float*)P0)[(size_t)r * N + c] = v;
                } else if (MODE == 3) {
                    if (r < Mlog) {
                        float xl = alpha[r] * (v + bias[c]);
                        float s = 1.f / (1.f + __expf(xl));
                        float w2 = s * s;
                        ((float*)P0)[(size_t)r * N + c] =
                            2.f * xl * w2 + 2.f * extra[(size_t)r * N + c] * (1.f - w2);
                    }
                } else if (MODE == 4) {
                    ((ushort*)P0)[(size_t)h * sC + (size_t)r * N + c] = f2b(v * scale);
                }
            }
        }
        if (MODE == 4 || MODE == 5) {
            int r0v = row0 + wm * Wr + mf * 16 + (l >> 4) * 4;
            int c = col0 + wn * Wr + nf * 16 + lr;
            ushort4 pk;
            pk.x = f2b(acc[mf][nf][0] * scale); pk.y = f2b(acc[mf][nf][1] * scale);
            pk.z = f2b(acc[mf][nf][2] * scale); pk.w = f2b(acc[mf][nf][3] * scale);
            *(ushort4*)&((ushort*)P1)[(size_t)h * sC + (size_t)c * Mlog + r0v] = pk;
        }
        if (MODE == 0) {
            // V^T pack: for V frags (c>>9 == 2), write Vt[h][d][NPAD]
            int c = col0 + wn * Wr + nf * 16 + lr;
            if ((c >> 9) == 2) {
                int hh = (c >> 6) & 7, d = c & 63;
                int r0v = row0 + wm * Wr + mf * 16 + (l >> 4) * 4;
                ushort4 pk;
                pk.x = f2b(acc[mf][nf][0]); pk.y = f2b(acc[mf][nf][1]);
                pk.z = f2b(acc[mf][nf][2]); pk.w = f2b(acc[mf][nf][3]);
                *(ushort4*)&((ushort*)P3)[((size_t)hh * DH + d) * NPAD + r0v] = pk;
            }
        }
    }
}

// ---------------------------------------------------------------- landmarks
__global__ void landmark_k(const ushort* __restrict__ src, ushort* __restrict__ dst)
{
    int b = blockIdx.x;
    int hh = b >> 8, j = b & 255, d = threadIdx.x;
    const ushort* p = src + ((size_t)hh * NPAD + (size_t)j * LFAC) * DH + d;
    float s = 0.f;
    #pragma unroll
    for (int t = 0; t < LFAC; ++t) s += b2f(p[t * DH]);
    dst[((size_t)hh * LM + j) * DH + d] = f2b(s * (1.f / LFAC));
}

// attn2 = softmax(q_l @ k_l^T)
__global__ __launch_bounds__(256)
void attn2_k(const ushort* __restrict__ QL, const ushort* __restrict__ KL,
             ushort* __restrict__ X2b)
{
    int i = blockIdx.x, h = blockIdx.y, j = threadIdx.x;
    __shared__ float qv[DH];
    __shared__ float red[256];
    if (j < DH) qv[j] = b2f(QL[((size_t)h * LM + i) * DH + j]);
    __syncthreads();
    const ushort* kp = KL + ((size_t)h * LM + j) * DH;
    float dot = 0.f;
    #pragma unroll
    for (int d = 0; d < DH; ++d) dot += qv[d] * b2f(kp[d]);
    red[j] = dot; __syncthreads();
    for (int s = 128; s > 0; s >>= 1) { if (j < s) red[j] = fmaxf(red[j], red[j + s]); __syncthreads(); }
    float mx = red[0]; __syncthreads();
    float e = __expf(dot - mx);
    red[j] = e; __syncthreads();
    for (int s = 128; s > 0; s >>= 1) { if (j < s) red[j] += red[j + s]; __syncthreads(); }
    X2b[((size_t)h * LM + i) * LM + j] = f2b(e / red[0]);
}

__global__ __launch_bounds__(256)
void colrow_k(const ushort* __restrict__ X2b, unsigned int* __restrict__ mx)
{
    int h = blockIdx.x, t = threadIdx.x;
    const ushort* x = X2b + (size_t)h * LM * LM;
    float cs = 0.f, rs = 0.f;
    for (int j = 0; j < LM; ++j) cs += fabsf(b2f(x[(size_t)t * LM + j]));
    for (int i = 0; i < LM; ++i) rs += fabsf(b2f(x[(size_t)i * LM + t]));
    __shared__ float r1[256], r2[256];
    r1[t] = cs; r2[t] = rs; __syncthreads();
    for (int s = 128; s > 0; s >>= 1) {
        if (t < s) { r1[t] = fmaxf(r1[t], r1[t + s]); r2[t] = fmaxf(r2[t], r2[t + s]); }
        __syncthreads();
    }
    if (t == 0) {
        atomicMax(&mx[0], __float_as_uint(r1[0]));
        atomicMax(&mx[1], __float_as_uint(r2[0]));
    }
}

__global__ void zinit_k(const ushort* __restrict__ X2b, const float* __restrict__ mxf,
                        ushort* __restrict__ Z, ushort* __restrict__ Zt)
{
    int i = blockIdx.x, h = blockIdx.y, j = threadIdx.x;
    float scale = 1.f / (mxf[0] * mxf[1]);
    float x = b2f(X2b[((size_t)h * LM + i) * LM + j]) * scale;
    ushort u = f2b(x);
    Z[((size_t)h * LM + j) * LM + i] = u;
    Zt[((size_t)h * LM + i) * LM + j] = u;
}

// ---------------------------------------------------------------- attn3: flash MFMA
// split-KV: grid (NSPLIT, 2 qtiles, 8 heads); per block 128 q-rows, 640 keys.
__global__ __launch_bounds__(256)
void attn3_fa(const ushort* __restrict__ QLb, const ushort* __restrict__ Kb,
              const ushort* __restrict__ Vt,
              float* __restrict__ Opart, float* __restrict__ Mpart,
              float* __restrict__ Lpart)
{
    __shared__ __align__(16) char smem[18432 + 32768];
    ushort* Qs = (ushort*)smem;               // [128][72]
    ushort* Ks = (ushort*)(smem + 18432);     // [128][72] (overlapped by Ps)
    ushort* Ps = (ushort*)(smem + 18432);     // [128][128] swizzled
    const int tid = threadIdx.x, l = tid & 63, wv = tid >> 6;
    const int split = blockIdx.x, qt = blockIdx.y, h = blockIdx.z;
    const int lr = l & 15, lg = l >> 4;
    {   // Q tile: 128 rows x 64 cols
        int row = tid >> 1, half = (tid & 1) * 32;
        const uint4* src = (const uint4*)(QLb + ((size_t)h * LM + qt * 128 + row) * DH + half);
        #pragma unroll
        for (int e = 0; e < 4; ++e) *(uint4*)&Qs[row * 72 + half + e * 8] = src[e];
    }
    f32x4 o[2][4];
    float m_[2][4], l_[2][4];
    #pragma unroll
    for (int mf = 0; mf < 2; ++mf) {
        #pragma unroll
        for (int nf = 0; nf < 4; ++nf) o[mf][nf] = (f32x4){0.f, 0.f, 0.f, 0.f};
        #pragma unroll
        for (int i = 0; i < 4; ++i) { m_[mf][i] = -INFINITY; l_[mf][i] = 0.f; }
    }
    const int k0base = split * (NPAD / NSPLIT);
    for (int ch = 0; ch < NPAD / NSPLIT / KCH; ++ch) {
        int kg0 = k0base + ch * KCH;
        __syncthreads();   // prev Ps consumed (and Qs ready on ch=0)
        {   // K chunk: 128 rows x 64
            int row = tid >> 1, half = (tid & 1) * 32;
            const uint4* src = (const uint4*)(Kb + ((size_t)h * NPAD + kg0 + row) * DH + half);
            #pragma unroll
            for (int e = 0; e < 4; ++e) *(uint4*)&Ks[row * 72 + half + e * 8] = src[e];
        }
        __syncthreads();
        f32x4 s[2][8];
        #pragma unroll
        for (int mf = 0; mf < 2; ++mf)
            #pragma unroll
            for (int nf = 0; nf < 8; ++nf) s[mf][nf] = (f32x4){0.f, 0.f, 0.f, 0.f};
        #pragma unroll
        for (int ks = 0; ks < 2; ++ks) {
            bf16x8 a0 = *(const bf16x8*)&Qs[(wv * 32 + 0 + lr) * 72 + ks * 32 + lg * 8];
            bf16x8 a1 = *(const bf16x8*)&Qs[(wv * 32 + 16 + lr) * 72 + ks * 32 + lg * 8];
            #pragma unroll
            for (int nf = 0; nf < 8; ++nf) {
                bf16x8 b = *(const bf16x8*)&Ks[(nf * 16 + lr) * 72 + ks * 32 + lg * 8];
                s[0][nf] = MFMA16(a0, b, s[0][nf]);
                s[1][nf] = MFMA16(a1, b, s[1][nf]);
            }
        }
        // online softmax update
        float scl[2][4];
        #pragma unroll
        for (int mf = 0; mf < 2; ++mf)
        #pragma unroll
        for (int i = 0; i < 4; ++i) {
            float mx = s[mf][0][i];
            #pragma unroll
            for (int nf = 1; nf < 8; ++nf) mx = fmaxf(mx, s[mf][nf][i]);
            mx = fmaxf(mx, __shfl_xor(mx, 1)); mx = fmaxf(mx, __shfl_xor(mx, 2));
            mx = fmaxf(mx, __shfl_xor(mx, 4)); mx = fmaxf(mx, __shfl_xor(mx, 8));
            float mn = fmaxf(m_[mf][i], mx);
            float sum = 0.f;
            #pragma unroll
            for (int nf = 0; nf < 8; ++nf) {
                float e = __expf(s[mf][nf][i] - mn); s[mf][nf][i] = e; sum += e;
            }
            sum += __shfl_xor(sum, 1); sum += __shfl_xor(sum, 2);
            sum += __shfl_xor(sum, 4); sum += __shfl_xor(sum, 8);
            float sc = __expf(m_[mf][i] - mn);
            l_[mf][i] = l_[mf][i] * sc + sum;
            m_[mf][i] = mn;
            scl[mf][i] = sc;
        }
        #pragma unroll
        for (int mf = 0; mf < 2; ++mf)
        #pragma unroll
        for (int nf = 0; nf < 4; ++nf)
        #pragma unroll
        for (int i = 0; i < 4; ++i) o[mf][nf][i] *= scl[mf][i];
        __syncthreads();   // all waves done reading Ks
        #pragma unroll
        for (int mf = 0; mf < 2; ++mf)
        #pragma unroll
        for (int nf = 0; nf < 8; ++nf)
        #pragma unroll
        for (int i = 0; i < 4; ++i) {
            int row = wv * 32 + mf * 16 + lg * 4 + i;
            int col = nf * 16 + lr;
            Ps[row * 128 + (col ^ ((row & 7) << 3))] = f2b(s[mf][nf][i]);
        }
        __syncthreads();
        #pragma unroll
        for (int ks = 0; ks < 4; ++ks) {
            bf16x8 a[2];
            #pragma unroll
            for (int mf = 0; mf < 2; ++mf) {
                int row = wv * 32 + mf * 16 + lr;
                int kcol = ks * 32 + lg * 8;
                a[mf] = *(const bf16x8*)&Ps[row * 128 + (kcol ^ ((row & 7) << 3))];
            }
            #pragma unroll
            for (int nf = 0; nf < 4; ++nf) {
                int d = nf * 16 + lr;
                bf16x8 b = *(const bf16x8*)(Vt + ((size_t)h * DH + d) * NPAD + kg0 + ks * 32 + lg * 8);
                #pragma unroll
                for (int mf = 0; mf < 2; ++mf) o[mf][nf] = MFMA16(a[mf], b, o[mf][nf]);
            }
        }
    }
    // write partials
    const int base = (split * 2 + qt) * 8 + h;
    #pragma unroll
    for (int mf = 0; mf < 2; ++mf)
    #pragma unroll
    for (int nf = 0; nf < 4; ++nf)
    #pragma unroll
    for (int i = 0; i < 4; ++i) {
        int r = wv * 32 + mf * 16 + lg * 4 + i;
        int c = nf * 16 + lr;
        Opart[((size_t)base * 128 + r) * 64 + c] = o[mf][nf][i];
    }
    if (lr == 0) {
        #pragma unroll
        for (int mf = 0; mf < 2; ++mf)
        #pragma unroll
        for (int i = 0; i < 4; ++i) {
            int r = wv * 32 + mf * 16 + lg * 4 + i;
            Mpart[base * 128 + r] = m_[mf][i];
            Lpart[base * 128 + r] = l_[mf][i];
        }
    }
}

// merge split-KV partials -> AVt[h][d][i] bf16
__global__ __launch_bounds__(256)
void mergeAV_k(const float* __restrict__ Opart, const float* __restrict__ Mpart,
               const float* __restrict__ Lpart, ushort* __restrict__ AVt)
{
    int qt = blockIdx.x, h = blockIdx.y, rq = blockIdx.z;
    int t = threadIdx.x;
    int r = rq * 32 + (t >> 3), c0 = (t & 7) * 8;
    float mv[NSPLIT];
    float mstar = -INFINITY;
    #pragma unroll
    for (int s = 0; s < NSPLIT; ++s) {
        mv[s] = Mpart[((s * 2 + qt) * 8 + h) * 128 + r];
        mstar = fmaxf(mstar, mv[s]);
    }
    float wgt[NSPLIT];
    float L = 0.f;
    #pragma unroll
    for (int s = 0; s < NSPLIT; ++s) {
        wgt[s] = __expf(mv[s] - mstar);
        L += wgt[s] * Lpart[((s * 2 + qt) * 8 + h) * 128 + r];
    }
    float inv = 1.f / L;
    float acc[8] = {};
    #pragma unroll
    for (int s = 0; s < NSPLIT; ++s) {
        const float* op = Opart + (((size_t)(s * 2 + qt) * 8 + h) * 128 + r) * 64 + c0;
        #pragma unroll
        for (int e = 0; e < 8; ++e) acc[e] += wgt[s] * op[e];
    }
    #pragma unroll
    for (int e = 0; e < 8; ++e)
        AVt[((size_t)h * DH + c0 + e) * LM + qt * 128 + r] = f2b(acc[e] * inv);
}

// depthwise conv residual -> OBf fp32 [10000][512]
__global__ __launch_bounds__(256)
void conv_k(const ushort* __restrict__ Vb, const float* __restrict__ cw,
            float* __restrict__ OBf)
{
    int idx = blockIdx.x * 256 + threadIdx.x;
    if (idx >= NSEQ * 128) return;
    int ro = idx >> 7, c4 = idx & 127;
    int h = c4 >> 4, dq = (c4 & 15) * 4;
    int i = ro + PADR;
    float a0 = 0, a1 = 0, a2 = 0, a3 = 0;
    #pragma unroll
    for (int tt = 0; tt < 33; ++tt) {
        int src = i + tt - 16;
        if (src < NPAD) {
            float wv = cw[h * 33 + tt];
            ushort4 u = *(const ushort4*)(Vb + ((size_t)h * NPAD + src) * DH + dq);
            a0 += wv * b2f(u.x); a1 += wv * b2f(u.y);
            a2 += wv * b2f(u.z); a3 += wv * b2f(u.w);
        }
    }
    *(float4*)&OBf[(size_t)ro * DMODEL + h * DH + dq] = make_float4(a0, a1, a2, a3);
}

// fused attn1 @ W + conv residual -> OBb bf16 [10000][512]
__global__ __launch_bounds__(256, 2)
void outrows_mfma(const ushort* __restrict__ Qb, const ushort* __restrict__ KLb,
                  const ushort* __restrict__ WTg, const float* __restrict__ OBf,
                  ushort* __restrict__ OBb)
{
    __shared__ __align__(16) char smem[65536];
    ushort* Qs = (ushort*)smem;                    // [128][72]
    ushort* KLs = (ushort*)(smem + 128 * 72 * 2);  // [256][72]
    ushort* Ps = (ushort*)smem;                    // [128][256] swizzled (phase 2)
    const int tid = threadIdx.x, l = tid & 63, w = tid >> 6;
    const int h = blockIdx.y, i0 = blockIdx.x * 128;
    const int lr = l & 15, lg = l >> 4;
    {
        int row = tid >> 1, half = (tid & 1) * 32;
        const uint4* src = (const uint4*)(Qb + ((size_t)h * NPAD + i0 + row) * DH + half);
        #pragma unroll
        for (int e = 0; e < 4; ++e) *(uint4*)&Qs[row * 72 + half + e * 8] = src[e];
    }
    {
        int row = tid;
        const uint4* src = (const uint4*)(KLb + ((size_t)h * LM + row) * DH);
        #pragma unroll
        for (int e = 0; e < 8; ++e) *(uint4*)&KLs[row * 72 + e * 8] = src[e];
    }
    __syncthreads();
    f32x4 s[2][16];
    #pragma unroll
    for (int mf = 0; mf < 2; ++mf)
        #pragma unroll
        for (int nf = 0; nf < 16; ++nf) s[mf][nf] = (f32x4){0.f, 0.f, 0.f, 0.f};
    #pragma unroll
    for (int ks = 0; ks < 2; ++ks) {
        bf16x8 a0 = *(const bf16x8*)&Qs[(w * 32 + 0 + lr) * 72 + ks * 32 + lg * 8];
        bf16x8 a1 = *(const bf16x8*)&Qs[(w * 32 + 16 + lr) * 72 + ks * 32 + lg * 8];
        #pragma unroll
        for (int nf = 0; nf < 16; ++nf) {
            bf16x8 b = *(const bf16x8*)&KLs[(nf * 16 + lr) * 72 + ks * 32 + lg * 8];
            s[0][nf] = MFMA16(a0, b, s[0][nf]);
            s[1][nf] = MFMA16(a1, b, s[1][nf]);
        }
    }
    float inv_[2][4];
    #pragma unroll
    for (int mf = 0; mf < 2; ++mf)
    #pragma unroll
    for (int i = 0; i < 4; ++i) {
        float m = s[mf][0][i];
        #pragma unroll
        for (int nf = 1; nf < 16; ++nf) m = fmaxf(m, s[mf][nf][i]);
        m = fmaxf(m, __shfl_xor(m, 1)); m = fmaxf(m, __shfl_xor(m, 2));
        m = fmaxf(m, __shfl_xor(m, 4)); m = fmaxf(m, __shfl_xor(m, 8));
        float sum = 0.f;
        #pragma unroll
        for (int nf = 0; nf < 16; ++nf) {
            float e = __expf(s[mf][nf][i] - m); s[mf][nf][i] = e; sum += e;
        }
        sum += __shfl_xor(sum, 1); sum += __shfl_xor(sum, 2);
        sum += __shfl_xor(sum, 4); sum += __shfl_xor(sum, 8);
        inv_[mf][i] = 1.f / sum;
    }
    __syncthreads();
    #pragma unroll
    for (int mf = 0; mf < 2; ++mf)
    #pragma unroll
    for (int nf = 0; nf < 16; ++nf)
    #pragma unroll
    for (int i = 0; i < 4; ++i) {
        int row = w * 32 + mf * 16 + lg * 4 + i;
        int col = nf * 16 + lr;
        Ps[row * 256 + (col ^ ((row & 7) << 3))] = f2b(s[mf][nf][i] * inv_[mf][i]);
    }
    __syncthreads();
    const int wm = w >> 1, wn = w & 1;
    f32x4 o[4][2];
    #pragma unroll
    for (int mf = 0; mf < 4; ++mf)
        #pragma unroll
        for (int nf = 0; nf < 2; ++nf) o[mf][nf] = (f32x4){0.f, 0.f, 0.f, 0.f};
    #pragma unroll
    for (int ks = 0; ks < 8; ++ks) {
        bf16x8 a[4];
        #pragma unroll
        for (int mf = 0; mf < 4; ++mf) {
            int row = wm * 64 + mf * 16 + lr;
            int kcol = ks * 32 + lg * 8;
            a[mf] = *(const bf16x8*)&Ps[row * 256 + (kcol ^ ((row & 7) << 3))];
        }
        #pragma unroll
        for (int nf = 0; nf < 2; ++nf) {
            int d = wn * 32 + nf * 16 + lr;
            bf16x8 b = *(const bf16x8*)(WTg + ((size_t)h * DH + d) * LM + ks * 32 + lg * 8);
            #pragma unroll
            for (int mf = 0; mf < 4; ++mf) o[mf][nf] = MFMA16(a[mf], b, o[mf][nf]);
        }
    }
    #pragma unroll
    for (int mf = 0; mf < 4; ++mf)
    #pragma unroll
    for (int nf = 0; nf < 2; ++nf)
    #pragma unroll
    for (int i = 0; i < 4; ++i) {
        int r = i0 + wm * 64 + mf * 16 + lg * 4 + i;
        if (r >= PADR) {
            int ro = r - PADR;
            int c = h * DH + wn * 32 + nf * 16 + lr;
            float v = o[mf][nf][i] + OBf[(size_t)ro * DMODEL + c];
            OBb[(size_t)ro * DMODEL + c] = f2b(v);
        }
    }
}

// ---------------------------------------------------------------- tail ops
__global__ __launch_bounds__(256)
void edges_k(const int* __restrict__ rows, const int* __restrict__ cols,
             const float* __restrict__ vals,
             const float* __restrict__ QE, const float* __restrict__ KE,
             float* __restrict__ A_raw, int E)
{
    int gid = blockIdx.x * blockDim.x + threadIdx.x;
    int e = gid >> 6, l = gid & 63;
    if (e >= E) return;
    int r = rows[e], c = cols[e];
    const float* qp = QE + (size_t)r * DQK;
    const float* kp = KE + (size_t)c * DQK;
    float dot = 0.f;
    #pragma unroll
    for (int d = l; d < DQK; d += 64) dot += qp[d] * kp[d];
    #pragma unroll
    for (int s = 32; s > 0; s >>= 1) dot += __shfl_down(dot, s);
    if (l == 0) atomicAdd(&A_raw[r], vals[e] * dot * 0.0625f);
}

__global__ __launch_bounds__(1024)
void alphasm_k(const float* __restrict__ A_raw, float* __restrict__ alpha)
{
    __shared__ float red[1024];
    int t = threadIdx.x;
    float lm = -INFINITY;
    for (int i = t; i < NSEQ; i += 1024) lm = fmaxf(lm, A_raw[i]);
    red[t] = lm; __syncthreads();
    for (int s = 512; s > 0; s >>= 1) { if (t < s) red[t] = fmaxf(red[t], red[t + s]); __syncthreads(); }
    float mx = red[0]; __syncthreads();
    float ls = 0.f;
    for (int i = t; i < NSEQ; i += 1024) ls += __expf(A_raw[i] - mx);
    red[t] = ls; __syncthreads();
    for (int s = 512; s > 0; s >>= 1) { if (t < s) red[t] += red[t + s]; __syncthreads(); }
    float inv = 1.f / red[0];
    for (int i = t; i < NSEQ; i += 1024) alpha[i] = __expf(A_raw[i] - mx) * inv;
}

__global__ void init_k(float* __restrict__ out, const float* __restrict__ fcb,
                       unsigned int* __restrict__ mx)
{
    int t = blockIdx.x * blockDim.x + threadIdx.x;
    if (t == 0) { out[0] = fcb[0]; mx[0] = 0u; mx[1] = 0u; }
    if (t >= 1 && t <= NSEQ) out[t] = 0.f;
    if (t >= NSEQ + 1 && t < OUTSZ) out[t] = 1.0f;
}

__global__ __launch_bounds__(256)
void pooled_k(const float* __restrict__ XO, const float* __restrict__ fc,
              float* __restrict__ out0)
{
    __shared__ float red[256];
    int t = threadIdx.x;
    float acc = 0.f;
    const size_t total = (size_t)NSEQ * DMODEL;
    for (size_t idx = (size_t)blockIdx.x * 256 + t; idx < total; idx += (size_t)gridDim.x * 256) {
        int d = (int)(idx & (DMODEL - 1));
        acc += XO[idx] * fc[d];
    }
    red[t] = acc; __syncthreads();
    for (int s = 128; s > 0; s >>= 1) { if (t < s) red[t] += red[t + s]; __syncthreads(); }
    if (t == 0) atomicAdd(out0, red[0]);
}

// ---------------------------------------------------------------- launch
extern "C" void kernel_launch(void* const* d_in, const int* in_sizes, int n_in,
                              void* d_out, int out_size, void* d_ws, size_t ws_size,
                              hipStream_t stream)
{
    (void)n_in; (void)out_size; (void)ws_size;
    const float* bag   = (const float*)d_in[0];
    const int*   arow  = (const int*)d_in[1];
    const int*   acol  = (const int*)d_in[2];
    const float* aval  = (const float*)d_in[3];
    const float* w_qkv = (const float*)d_in[4];
    const float* w_out = (const float*)d_in[5];
    const float* b_out = (const float*)d_in[6];
    const float* convw = (const float*)d_in[7];
    const float* wq    = (const float*)d_in[8];
    const float* wk    = (const float*)d_in[9];
    const float* wv_w  = (const float*)d_in[10];
    const float* wv_b  = (const float*)d_in[11];
    const float* fck   = (const float*)d_in[15];
    const float* fcb   = (const float*)d_in[16];
    const int E = in_sizes[1];
    float* out = (float*)d_out;

    char* ws = (char*)d_ws;
    size_t off = 0;
    auto alloc = [&](size_t bytes) { void* p = ws + off; off += (bytes + 255) & ~(size_t)255; return p; };
    ushort* Qb    = (ushort*)alloc((size_t)HEADS * NPAD * DH * 2);
    ushort* Kb    = (ushort*)alloc((size_t)HEADS * NPAD * DH * 2);
    ushort* Vb    = (ushort*)alloc((size_t)HEADS * NPAD * DH * 2);
    ushort* bagb  = (ushort*)alloc((size_t)NSEQ * DMODEL * 2);
    ushort* wqkvT = (ushort*)alloc((size_t)1536 * 512 * 2);
    ushort* woutT = (ushort*)alloc((size_t)512 * 512 * 2);
    ushort* wqT   = (ushort*)alloc((size_t)256 * 512 * 2);
    ushort* wkT   = (ushort*)alloc((size_t)256 * 512 * 2);
    ushort* wvwT  = (ushort*)alloc((size_t)512 * 512 * 2);
    ushort* QLb   = (ushort*)alloc((size_t)HEADS * LM * DH * 2);
    ushort* KLb   = (ushort*)alloc((size_t)HEADS * LM * DH * 2);
    ushort* X2b   = (ushort*)alloc((size_t)HEADS * LM * LM * 2);
    ushort* Za    = (ushort*)alloc((size_t)HEADS * LM * LM * 2);
    ushort* Zat   = (ushort*)alloc((size_t)HEADS * LM * LM * 2);
    ushort* Zb2   = (ushort*)alloc((size_t)HEADS * LM * LM * 2);
    ushort* Zbt2  = (ushort*)alloc((size_t)HEADS * LM * LM * 2);
    ushort* T0    = (ushort*)alloc((size_t)HEADS * LM * LM * 2);
    ushort* T0t   = (ushort*)alloc((size_t)HEADS * LM * LM * 2);
    ushort* T1t   = (ushort*)alloc((size_t)HEADS * LM * LM * 2);
    ushort* T2t   = (ushort*)alloc((size_t)HEADS * LM * LM * 2);
    ushort* AVt   = (ushort*)alloc((size_t)HEADS * DH * LM * 2);
    ushort* WT    = (ushort*)alloc((size_t)HEADS * DH * LM * 2);
    float*  OBf   = (float*)alloc((size_t)NSEQ * DMODEL * 4);
    ushort* OBb   = (ushort*)alloc((size_t)NSEQ * DMODEL * 2);
    float*  ENCf  = (float*)alloc((size_t)NSEQ * DMODEL * 4);
    ushort* ENCb  = (ushort*)alloc((size_t)NSEQ * DMODEL * 2);
    float*  ALPHA = (float*)alloc((size_t)NPAD * 4);
    float*  MXf   = (float*)alloc(256);
    unsigned int* MX = (unsigned int*)MXf;
    // aliases (disjoint lifetimes)
    float* QE = (float*)Qb;           // fp32 10000x256 (after Qb dead)
    float* KE = (float*)Kb;
    float* XO = OBf;
    // attn3 scratch aliases ENC region (ENC written only later)
    ushort* Vt    = (ushort*)ENCf;                          // 10.49 MB <= 20.48 MB
    float*  Opart = (float*)ENCb;                           // 8.39 MB
    float*  Mpart = (float*)((char*)ENCb + 8388608);        // 128 KB
    float*  Lpart = (float*)((char*)ENCb + 8519680);        // 128 KB  (<= 10.24 MB)

    const long ZS = (long)LM * LM;
    const long WS = (long)DH * LM;

    init_k<<<(OUTSZ + 255) / 256, 256, 0, stream>>>(out, fcb, MX);

    cvt_k<<<(NSEQ * DMODEL / 4 + 255) / 256, 256, 0, stream>>>(bag, bagb, NSEQ * DMODEL / 4);
    tcvt_k<<<dim3(1536 / 32, 512 / 32), 256, 0, stream>>>(w_qkv, wqkvT, 512, 1536);
    tcvt_k<<<dim3(512 / 32, 512 / 32), 256, 0, stream>>>(w_out, woutT, 512, 512);
    tcvt_k<<<dim3(256 / 32, 512 / 32), 256, 0, stream>>>(wq, wqT, 512, 256);
    tcvt_k<<<dim3(256 / 32, 512 / 32), 256, 0, stream>>>(wk, wkT, 512, 256);
    tcvt_k<<<dim3(512 / 32, 512 / 32), 256, 0, stream>>>(wv_w, wvwT, 512, 512);

    // QKV projection (+ V^T pack)
    mgemm<128, 0, false><<<dim3(12, 80, 1), 256, 0, stream>>>(
        bagb, wqkvT, NPAD, 1536, 512, PADR, 0, 0, 0, 0.f, 1.f,
        Qb, Kb, Vb, Vt, nullptr, nullptr, nullptr);

    landmark_k<<<HEADS * LM, DH, 0, stream>>>(Qb, QLb);
    landmark_k<<<HEADS * LM, DH, 0, stream>>>(Kb, KLb);

    attn2_k<<<dim3(LM, HEADS), 256, 0, stream>>>(QLb, KLb, X2b);
    colrow_k<<<HEADS, 256, 0, stream>>>(X2b, MX);
    zinit_k<<<dim3(LM, HEADS), 256, 0, stream>>>(X2b, MXf, Za, Zat);

    // Newton-Schulz pinv
    ushort *Z = Za, *Zt = Zat, *Zn = Zb2, *Znt = Zbt2;
    for (int it = 0; it < 6; ++it) {
        mgemm<64, 4, false><<<dim3(4, 4, HEADS), 256, 0, stream>>>(
            X2b, Zt, LM, LM, LM, 0, ZS, ZS, ZS, 0.f, 1.f,
            T0, T0t, nullptr, nullptr, nullptr, nullptr, nullptr);
        mgemm<64, 5, true><<<dim3(4, 4, HEADS), 256, 0, stream>>>(
            T0, T0t, LM, LM, LM, 0, ZS, ZS, ZS, 7.f, 1.f,
            nullptr, T1t, nullptr, nullptr, nullptr, nullptr, nullptr);
        mgemm<64, 5, true><<<dim3(4, 4, HEADS), 256, 0, stream>>>(
            T0, T1t, LM, LM, LM, 0, ZS, ZS, ZS, 15.f, 1.f,
            nullptr, T2t, nullptr, nullptr, nullptr, nullptr, nullptr);
        mgemm<64, 4, true><<<dim3(4, 4, HEADS), 256, 0, stream>>>(
            Z, T2t, LM, LM, LM, 0, ZS, ZS, ZS, 13.f, 0.25f,
            Zn, Znt, nullptr, nullptr, nullptr, nullptr, nullptr);
        ushort* t;
        t = Z; Z = Zn; Zn = t;
        t = Zt; Zt = Znt; Znt = t;
    }

    // attn3 @ v (flash, split-KV) -> merge -> AVt; then W^T = (Z @ AV)^T
    attn3_fa<<<dim3(NSPLIT, 2, HEADS), 256, 0, stream>>>(QLb, Kb, Vt, Opart, Mpart, Lpart);
    mergeAV_k<<<dim3(2, HEADS, 4), 256, 0, stream>>>(Opart, Mpart, Lpart, AVt);
    mgemm<64, 5, false><<<dim3(1, 4, HEADS), 256, 0, stream>>>(
        Z, AVt, LM, DH, LM, 0, ZS, WS, WS, 0.f, 1.f,
        nullptr, WT, nullptr, nullptr, nullptr, nullptr, nullptr);

    // conv residual, then fused attn1 @ W + residual
    conv_k<<<(NSEQ * 128 + 255) / 256, 256, 0, stream>>>(Vb, convw, OBf);
    outrows_mfma<<<dim3(NPAD / 128, HEADS), 256, 0, stream>>>(Qb, KLb, WT, OBf, OBb);

    // enc = out_buf @ w_out + b_out + bag
    mgemm<128, 1, false><<<dim3(4, 79), 256, 0, stream>>>(
        OBb, woutT, NSEQ, DMODEL, 512, 0, 0, 0, 0, 0.f, 1.f,
        ENCf, ENCb, nullptr, nullptr, b_out, bag, nullptr);

    // qe / ke
    mgemm<128, 2, false><<<dim3(2, 79), 256, 0, stream>>>(
        ENCb, wqT, NSEQ, DQK, 512, 0, 0, 0, 0, 0.f, 1.f,
        QE, nullptr, nullptr, nullptr, nullptr, nullptr, nullptr);
    mgemm<128, 2, false><<<dim3(2, 79), 256, 0, stream>>>(
        ENCb, wkT, NSEQ, DQK, 512, 0, 0, 0, 0, 0.f, 1.f,
        KE, nullptr, nullptr, nullptr, nullptr, nullptr, nullptr);

    // sparse edges -> A_raw, softmax -> alpha
    edges_k<<<(E * 64 + 255) / 256, 256, 0, stream>>>(arow, acol, aval, QE, KE, out + 1, E);
    alphasm_k<<<1, 1024, 0, stream>>>(out + 1, ALPHA);

    // value + xo epilogue
    mgemm<128, 3, false><<<dim3(4, 79), 256, 0, stream>>>(
        bagb, wvwT, NSEQ, DMODEL, 512, 0, 0, 0, 0, 0.f, 1.f,
        XO, nullptr, nullptr, nullptr, wv_b, ENCf, ALPHA);

    pooled_k<<<160, 256, 0, stream>>>(XO, fck, out);
}

// Round 5
// 512.097 us; speedup vs baseline: 5.7520x; 1.0716x over previous
//
#include <hip/hip_runtime.h>
#include <hip/hip_bf16.h>
#include <math.h>

#define NSEQ   10000
#define NPAD   10240
#define PADR   240
#define HEADS  8
#define DH     64
#define LM     256
#define LFAC   40
#define DMODEL 512
#define DQK    256
#define OUTSZ  20001
#define NSPLIT 16
#define KCH    128

typedef __attribute__((ext_vector_type(8))) short bf16x8;
typedef __attribute__((ext_vector_type(4))) float f32x4;
#define MFMA16(a,b,c) __builtin_amdgcn_mfma_f32_16x16x32_bf16(a,b,c,0,0,0)

__device__ __forceinline__ float b2f(ushort u) {
    return __uint_as_float(((unsigned)u) << 16);
}
__device__ __forceinline__ ushort f2b(float f) {
    unsigned u = __float_as_uint(f);
    unsigned r = (u + 0x7FFFu + ((u >> 16) & 1u)) >> 16;
    return (ushort)r;
}
// bijective XCD-chunk swizzle (m204): executing block bid takes logical work w
__device__ __forceinline__ int swz8(int bid, int nwg) {
    int q = nwg >> 3, r = nwg & 7;
    int x = bid & 7, idx = bid >> 3;
    int start = (x < r) ? x * (q + 1) : r * (q + 1) + (x - r) * q;
    return start + idx;
}

// ---------------------------------------------------------------- converts
__global__ __launch_bounds__(256) void cvt_k(const float* __restrict__ in,
                                             ushort* __restrict__ out, int n4)
{
    int i = blockIdx.x * 256 + threadIdx.x;
    if (i < n4) {
        float4 v = ((const float4*)in)[i];
        ushort4 u; u.x = f2b(v.x); u.y = f2b(v.y); u.z = f2b(v.z); u.w = f2b(v.w);
        ((ushort4*)out)[i] = u;
    }
}

// all weight transposes in one kernel: concat column space 3072, rows 512
__global__ __launch_bounds__(256)
void wtrans_k(const float* __restrict__ w_qkv, const float* __restrict__ w_out,
              const float* __restrict__ wq, const float* __restrict__ wk,
              const float* __restrict__ wv_w,
              ushort* __restrict__ wqkvT, ushort* __restrict__ woutT,
              ushort* __restrict__ wqkT, ushort* __restrict__ wvwT)
{
    __shared__ float tile[32][33];
    int g0 = blockIdx.x * 32, r0 = blockIdx.y * 32;
    const float* in; ushort* outp; int C; int lc0;
    if (g0 < 1536)      { in = w_qkv; outp = wqkvT;          C = 1536; lc0 = g0; }
    else if (g0 < 2048) { in = w_out; outp = woutT;          C = 512;  lc0 = g0 - 1536; }
    else if (g0 < 2304) { in = wq;    outp = wqkT;           C = 256;  lc0 = g0 - 2048; }
    else if (g0 < 2560) { in = wk;    outp = wqkT + 256*512; C = 256;  lc0 = g0 - 2304; }
    else                { in = wv_w;  outp = wvwT;           C = 512;  lc0 = g0 - 2560; }
    int tx = threadIdx.x & 31, ty = threadIdx.x >> 5;
    for (int i = ty; i < 32; i += 8) tile[i][tx] = in[(size_t)(r0 + i) * C + lc0 + tx];
    __syncthreads();
    for (int i = ty; i < 32; i += 8) outp[(size_t)(lc0 + i) * 512 + r0 + tx] = f2b(tile[tx][i]);
}

// ---------------------------------------------------------------- big MFMA GEMM (BM=128)
//  MODE 0: QKV split -> P0/P1/P2 bf16 [h][NPAD][64], q*0.125; P3 = V^T pack
//  MODE 1: o = v + bias[c] + extra[r][c] -> P0 fp32, P1 bf16   (enc)
//  MODE 3: xo epilogue (alpha, bias, extra=ENCf) -> P0 fp32
//  MODE 6: c<256 -> P0 (QE fp32), else P1 (KE fp32)
template<int MODE>
__global__ __launch_bounds__(256)
void mgemm(const ushort* __restrict__ A, const ushort* __restrict__ Bt,
           int Mlog, int N, int K, int padr, int nbx,
           void* __restrict__ P0, void* __restrict__ P1, void* __restrict__ P2,
           void* __restrict__ P3,
           const float* __restrict__ bias, const float* __restrict__ extra,
           const float* __restrict__ alpha)
{
    __shared__ ushort As[128 * 40];
    __shared__ ushort Bs[128 * 40];
    const int tid = threadIdx.x;
    const int l = tid & 63, w = tid >> 6;
    const int wm = w >> 1, wn = w & 1;
    const int wk_ = swz8(blockIdx.x, gridDim.x);
    const int row0 = (wk_ / nbx) * 128, col0 = (wk_ % nbx) * 128;
    const int lr = l & 15, lk = (l >> 4) * 8;
    f32x4 acc[4][4];
    #pragma unroll
    for (int i = 0; i < 4; ++i)
        #pragma unroll
        for (int j = 0; j < 4; ++j) acc[i][j] = (f32x4){0.f, 0.f, 0.f, 0.f};

    for (int k0 = 0; k0 < K; k0 += 32) {
        int row = tid >> 1, half = (tid & 1) * 16;
        {
            int phys = row0 + row - padr;
            uint4 v0 = {0,0,0,0}, v1 = {0,0,0,0};
            if (phys >= 0 && phys < Mlog - padr) {
                const uint4* src = (const uint4*)(A + (size_t)phys * K + k0 + half);
                v0 = src[0]; v1 = src[1];
            }
            *(uint4*)&As[row * 40 + half] = v0;
            *(uint4*)&As[row * 40 + half + 8] = v1;
        }
        {
            const uint4* src = (const uint4*)(Bt + (size_t)(col0 + row) * K + k0 + half);
            uint4 v0 = src[0], v1 = src[1];
            *(uint4*)&Bs[row * 40 + half] = v0;
            *(uint4*)&Bs[row * 40 + half + 8] = v1;
        }
        __syncthreads();
        bf16x8 af[4];
        #pragma unroll
        for (int mf = 0; mf < 4; ++mf)
            af[mf] = *(const bf16x8*)&As[(wm * 64 + mf * 16 + lr) * 40 + lk];
        #pragma unroll
        for (int nf = 0; nf < 4; ++nf) {
            bf16x8 bfr = *(const bf16x8*)&Bs[(wn * 64 + nf * 16 + lr) * 40 + lk];
            #pragma unroll
            for (int mf = 0; mf < 4; ++mf)
                acc[mf][nf] = MFMA16(af[mf], bfr, acc[mf][nf]);
        }
        __syncthreads();
    }

    #pragma unroll
    for (int mf = 0; mf < 4; ++mf)
    #pragma unroll
    for (int nf = 0; nf < 4; ++nf) {
        #pragma unroll
        for (int i = 0; i < 4; ++i) {
            int r = row0 + wm * 64 + mf * 16 + (l >> 4) * 4 + i;
            int c = col0 + wn * 64 + nf * 16 + lr;
            float v = acc[mf][nf][i];
            if (MODE == 0) {
                int t = c >> 9, hh = (c >> 6) & 7, d = c & 63;
                ushort* dst = (t == 0) ? (ushort*)P0 : (t == 1) ? (ushort*)P1 : (ushort*)P2;
                dst[((size_t)hh * NPAD + r) * DH + d] = f2b(t == 0 ? v * 0.125f : v);
            } else if (MODE == 1) {
                if (r < Mlog) {
                    float o = v + bias[c] + extra[(size_t)r * N + c];
                    ((float*)P0)[(size_t)r * N + c] = o;
                    ((ushort*)P1)[(size_t)r * N + c] = f2b(o);
                }
            } else if (MODE == 3) {
                if (r < Mlog) {
                    float xl = alpha[r] * (v + bias[c]);
                    float s = 1.f / (1.f + __expf(xl));
                    float w2 = s * s;
                    ((float*)P0)[(size_t)r * N + c] =
                        2.f * xl * w2 + 2.f * extra[(size_t)r * N + c] * (1.f - w2);
                }
            } else if (MODE == 6) {
                if (r < Mlog) {
                    if (c < 256) ((float*)P0)[(size_t)r * 256 + c] = v;
                    else         ((float*)P1)[(size_t)r * 256 + (c - 256)] = v;
                }
            }
        }
        if (MODE == 0) {
            int c = col0 + wn * 64 + nf * 16 + lr;
            if ((c >> 9) == 2) {
                int hh = (c >> 6) & 7, d = c & 63;
                int r0v = row0 + wm * 64 + mf * 16 + (l >> 4) * 4;
                ushort4 pk;
                pk.x = f2b(acc[mf][nf][0]); pk.y = f2b(acc[mf][nf][1]);
                pk.z = f2b(acc[mf][nf][2]); pk.w = f2b(acc[mf][nf][3]);
                *(ushort4*)&((ushort*)P3)[((size_t)hh * DH + d) * NPAD + r0v] = pk;
            }
        }
    }
}

// ---------------------------------------------------------------- pinv one-shot-K GEMM
// C(256xN) = A(256x256) @ B; Bt = B^T [N][256]; per-head batch (z).
// PLAIN: also write C (scaled) row-major; always write C^T (scaled) [N][256].
// BCI: B := cval*I - X where Bt holds X^T.
template<bool PLAIN, bool BCI>
__global__ __launch_bounds__(256)
void pinv_k(const ushort* __restrict__ A, const ushort* __restrict__ Bt,
            int N, float cval, float scale,
            ushort* __restrict__ P0, ushort* __restrict__ P1)
{
    __shared__ __align__(16) char smem[65536];
    char* As = smem;           // [64] rows x 512B, XOR-swizzled
    char* Bs = smem + 32768;
    const int tid = threadIdx.x, l = tid & 63, w = tid >> 6;
    const int wm = w >> 1, wn = w & 1;
    const int lr = l & 15, lg = l >> 4;
    const int col0 = blockIdx.x * 64, row0 = blockIdx.y * 64, h = blockIdx.z;
    const ushort* Ab = A + (size_t)h * 65536;
    const ushort* Btb = Bt + (size_t)h * ((size_t)N * 256);
    {
        int row = tid >> 2, seg = (tid & 3) * 128;   // byte offset within row
        const uint4* sa = (const uint4*)(Ab + (size_t)(row0 + row) * 256) + (tid & 3) * 8;
        const uint4* sb = (const uint4*)(Btb + (size_t)(col0 + row) * 256) + (tid & 3) * 8;
        int gn = col0 + row;
        #pragma unroll
        for (int e = 0; e < 8; ++e) {
            int off = (row * 512 + seg + e * 16) ^ ((row & 7) << 4);
            uint4 va = sa[e];
            *(uint4*)(As + off) = va;
            uint4 vb = sb[e];
            if (BCI) {
                union { uint4 u; ushort s[8]; } t; t.u = vb;
                int gk0 = (seg >> 1) + e * 8;
                #pragma unroll
                for (int j = 0; j < 8; ++j)
                    t.s[j] = f2b(((gn == gk0 + j) ? cval : 0.f) - b2f(t.s[j]));
                vb = t.u;
            }
            *(uint4*)(Bs + off) = vb;
        }
    }
    __syncthreads();
    f32x4 acc[2][2];
    #pragma unroll
    for (int i = 0; i < 2; ++i)
        #pragma unroll
        for (int j = 0; j < 2; ++j) acc[i][j] = (f32x4){0.f, 0.f, 0.f, 0.f};
    #pragma unroll
    for (int ks = 0; ks < 8; ++ks) {
        bf16x8 af[2], bf[2];
        #pragma unroll
        for (int mf = 0; mf < 2; ++mf) {
            int ar = wm * 32 + mf * 16 + lr;
            af[mf] = *(const bf16x8*)(As + ((ar * 512 + ks * 64 + lg * 16) ^ ((ar & 7) << 4)));
        }
        #pragma unroll
        for (int nf = 0; nf < 2; ++nf) {
            int br = wn * 32 + nf * 16 + lr;
            bf[nf] = *(const bf16x8*)(Bs + ((br * 512 + ks * 64 + lg * 16) ^ ((br & 7) << 4)));
        }
        #pragma unroll
        for (int mf = 0; mf < 2; ++mf)
            #pragma unroll
            for (int nf = 0; nf < 2; ++nf)
                acc[mf][nf] = MFMA16(af[mf], bf[nf], acc[mf][nf]);
    }
    #pragma unroll
    for (int mf = 0; mf < 2; ++mf)
    #pragma unroll
    for (int nf = 0; nf < 2; ++nf) {
        int r0v = row0 + wm * 32 + mf * 16 + lg * 4;
        int c = col0 + wn * 32 + nf * 16 + lr;
        if (PLAIN) {
            #pragma unroll
            for (int i = 0; i < 4; ++i)
                P0[(size_t)h * 256 * N + (size_t)(r0v + i) * N + c] = f2b(acc[mf][nf][i] * scale);
        }
        ushort4 pk;
        pk.x = f2b(acc[mf][nf][0] * scale); pk.y = f2b(acc[mf][nf][1] * scale);
        pk.z = f2b(acc[mf][nf][2] * scale); pk.w = f2b(acc[mf][nf][3] * scale);
        *(ushort4*)&P1[(size_t)h * ((size_t)N * 256) + (size_t)c * 256 + r0v] = pk;
    }
}

// ---------------------------------------------------------------- landmarks
__global__ void landmark_k(const ushort* __restrict__ src, ushort* __restrict__ dst)
{
    int b = blockIdx.x;
    int hh = b >> 8, j = b & 255, d = threadIdx.x;
    const ushort* p = src + ((size_t)hh * NPAD + (size_t)j * LFAC) * DH + d;
    float s = 0.f;
    #pragma unroll
    for (int t = 0; t < LFAC; ++t) s += b2f(p[t * DH]);
    dst[((size_t)hh * LM + j) * DH + d] = f2b(s * (1.f / LFAC));
}

// attn2 = softmax(q_l @ k_l^T)
__global__ __launch_bounds__(256)
void attn2_k(const ushort* __restrict__ QL, const ushort* __restrict__ KL,
             ushort* __restrict__ X2b)
{
    int i = blockIdx.x, h = blockIdx.y, j = threadIdx.x;
    __shared__ float qv[DH];
    __shared__ float red[256];
    if (j < DH) qv[j] = b2f(QL[((size_t)h * LM + i) * DH + j]);
    __syncthreads();
    const ushort* kp = KL + ((size_t)h * LM + j) * DH;
    float dot = 0.f;
    #pragma unroll
    for (int d = 0; d < DH; ++d) dot += qv[d] * b2f(kp[d]);
    red[j] = dot; __syncthreads();
    for (int s = 128; s > 0; s >>= 1) { if (j < s) red[j] = fmaxf(red[j], red[j + s]); __syncthreads(); }
    float mx = red[0]; __syncthreads();
    float e = __expf(dot - mx);
    red[j] = e; __syncthreads();
    for (int s = 128; s > 0; s >>= 1) { if (j < s) red[j] += red[j + s]; __syncthreads(); }
    X2b[((size_t)h * LM + i) * LM + j] = f2b(e / red[0]);
}

__global__ __launch_bounds__(256)
void colrow_k(const ushort* __restrict__ X2b, unsigned int* __restrict__ mx)
{
    int h = blockIdx.x, t = threadIdx.x;
    const ushort* x = X2b + (size_t)h * LM * LM;
    float cs = 0.f, rs = 0.f;
    for (int j = 0; j < LM; ++j) cs += fabsf(b2f(x[(size_t)t * LM + j]));
    for (int i = 0; i < LM; ++i) rs += fabsf(b2f(x[(size_t)i * LM + t]));
    __shared__ float r1[256], r2[256];
    r1[t] = cs; r2[t] = rs; __syncthreads();
    for (int s = 128; s > 0; s >>= 1) {
        if (t < s) { r1[t] = fmaxf(r1[t], r1[t + s]); r2[t] = fmaxf(r2[t], r2[t + s]); }
        __syncthreads();
    }
    if (t == 0) {
        atomicMax(&mx[0], __float_as_uint(r1[0]));
        atomicMax(&mx[1], __float_as_uint(r2[0]));
    }
}

__global__ void zinit_k(const ushort* __restrict__ X2b, const float* __restrict__ mxf,
                        ushort* __restrict__ Z, ushort* __restrict__ Zt)
{
    int i = blockIdx.x, h = blockIdx.y, j = threadIdx.x;
    float scale = 1.f / (mxf[0] * mxf[1]);
    float x = b2f(X2b[((size_t)h * LM + i) * LM + j]) * scale;
    ushort u = f2b(x);
    Z[((size_t)h * LM + j) * LM + i] = u;
    Zt[((size_t)h * LM + i) * LM + j] = u;
}

// ---------------------------------------------------------------- attn3: flash MFMA
__global__ __launch_bounds__(256)
void attn3_fa(const ushort* __restrict__ QLb, const ushort* __restrict__ Kb,
              const ushort* __restrict__ Vt,
              float* __restrict__ Opart, float* __restrict__ Mpart,
              float* __restrict__ Lpart)
{
    __shared__ __align__(16) char smem[18432 + 32768];
    ushort* Qs = (ushort*)smem;               // [128][72]
    ushort* Ks = (ushort*)(smem + 18432);     // [128][72] (overlapped by Ps)
    ushort* Ps = (ushort*)(smem + 18432);     // [128][128] swizzled
    const int tid = threadIdx.x, l = tid & 63, wv = tid >> 6;
    const int split = blockIdx.x, qt = blockIdx.y, h = blockIdx.z;
    const int lr = l & 15, lg = l >> 4;
    {
        int row = tid >> 1, half = (tid & 1) * 32;
        const uint4* src = (const uint4*)(QLb + ((size_t)h * LM + qt * 128 + row) * DH + half);
        #pragma unroll
        for (int e = 0; e < 4; ++e) *(uint4*)&Qs[row * 72 + half + e * 8] = src[e];
    }
    f32x4 o[2][4];
    float m_[2][4], l_[2][4];
    #pragma unroll
    for (int mf = 0; mf < 2; ++mf) {
        #pragma unroll
        for (int nf = 0; nf < 4; ++nf) o[mf][nf] = (f32x4){0.f, 0.f, 0.f, 0.f};
        #pragma unroll
        for (int i = 0; i < 4; ++i) { m_[mf][i] = -INFINITY; l_[mf][i] = 0.f; }
    }
    const int k0base = split * (NPAD / NSPLIT);
    for (int ch = 0; ch < NPAD / NSPLIT / KCH; ++ch) {
        int kg0 = k0base + ch * KCH;
        __syncthreads();
        {
            int row = tid >> 1, half = (tid & 1) * 32;
            const uint4* src = (const uint4*)(Kb + ((size_t)h * NPAD + kg0 + row) * DH + half);
            #pragma unroll
            for (int e = 0; e < 4; ++e) *(uint4*)&Ks[row * 72 + half + e * 8] = src[e];
        }
        __syncthreads();
        f32x4 s[2][8];
        #pragma unroll
        for (int mf = 0; mf < 2; ++mf)
            #pragma unroll
            for (int nf = 0; nf < 8; ++nf) s[mf][nf] = (f32x4){0.f, 0.f, 0.f, 0.f};
        #pragma unroll
        for (int ks = 0; ks < 2; ++ks) {
            bf16x8 a0 = *(const bf16x8*)&Qs[(wv * 32 + 0 + lr) * 72 + ks * 32 + lg * 8];
            bf16x8 a1 = *(const bf16x8*)&Qs[(wv * 32 + 16 + lr) * 72 + ks * 32 + lg * 8];
            #pragma unroll
            for (int nf = 0; nf < 8; ++nf) {
                bf16x8 b = *(const bf16x8*)&Ks[(nf * 16 + lr) * 72 + ks * 32 + lg * 8];
                s[0][nf] = MFMA16(a0, b, s[0][nf]);
                s[1][nf] = MFMA16(a1, b, s[1][nf]);
            }
        }
        float scl[2][4];
        #pragma unroll
        for (int mf = 0; mf < 2; ++mf)
        #pragma unroll
        for (int i = 0; i < 4; ++i) {
            float mx = s[mf][0][i];
            #pragma unroll
            for (int nf = 1; nf < 8; ++nf) mx = fmaxf(mx, s[mf][nf][i]);
            mx = fmaxf(mx, __shfl_xor(mx, 1)); mx = fmaxf(mx, __shfl_xor(mx, 2));
            mx = fmaxf(mx, __shfl_xor(mx, 4)); mx = fmaxf(mx, __shfl_xor(mx, 8));
            float mn = fmaxf(m_[mf][i], mx);
            float sum = 0.f;
            #pragma unroll
            for (int nf = 0; nf < 8; ++nf) {
                float e = __expf(s[mf][nf][i] - mn); s[mf][nf][i] = e; sum += e;
            }
            sum += __shfl_xor(sum, 1); sum += __shfl_xor(sum, 2);
            sum += __shfl_xor(sum, 4); sum += __shfl_xor(sum, 8);
            float sc = __expf(m_[mf][i] - mn);
            l_[mf][i] = l_[mf][i] * sc + sum;
            m_[mf][i] = mn;
            scl[mf][i] = sc;
        }
        #pragma unroll
        for (int mf = 0; mf < 2; ++mf)
        #pragma unroll
        for (int nf = 0; nf < 4; ++nf)
        #pragma unroll
        for (int i = 0; i < 4; ++i) o[mf][nf][i] *= scl[mf][i];
        __syncthreads();
        #pragma unroll
        for (int mf = 0; mf < 2; ++mf)
        #pragma unroll
        for (int nf = 0; nf < 8; ++nf)
        #pragma unroll
        for (int i = 0; i < 4; ++i) {
            int row = wv * 32 + mf * 16 + lg * 4 + i;
            int col = nf * 16 + lr;
            Ps[row * 128 + (col ^ ((row & 7) << 3))] = f2b(s[mf][nf][i]);
        }
        __syncthreads();
        #pragma unroll
        for (int ks = 0; ks < 4; ++ks) {
            bf16x8 a[2];
            #pragma unroll
            for (int mf = 0; mf < 2; ++mf) {
                int row = wv * 32 + mf * 16 + lr;
                int kcol = ks * 32 + lg * 8;
                a[mf] = *(const bf16x8*)&Ps[row * 128 + (kcol ^ ((row & 7) << 3))];
            }
            #pragma unroll
            for (int nf = 0; nf < 4; ++nf) {
                int d = nf * 16 + lr;
                bf16x8 b = *(const bf16x8*)(Vt + ((size_t)h * DH + d) * NPAD + kg0 + ks * 32 + lg * 8);
                #pragma unroll
                for (int mf = 0; mf < 2; ++mf) o[mf][nf] = MFMA16(a[mf], b, o[mf][nf]);
            }
        }
    }
    const int base = (split * 2 + qt) * 8 + h;
    #pragma unroll
    for (int mf = 0; mf < 2; ++mf)
    #pragma unroll
    for (int nf = 0; nf < 4; ++nf)
    #pragma unroll
    for (int i = 0; i < 4; ++i) {
        int r = wv * 32 + mf * 16 + lg * 4 + i;
        int c = nf * 16 + lr;
        Opart[((size_t)base * 128 + r) * 64 + c] = o[mf][nf][i];
    }
    if (lr == 0) {
        #pragma unroll
        for (int mf = 0; mf < 2; ++mf)
        #pragma unroll
        for (int i = 0; i < 4; ++i) {
            int r = wv * 32 + mf * 16 + lg * 4 + i;
            Mpart[base * 128 + r] = m_[mf][i];
            Lpart[base * 128 + r] = l_[mf][i];
        }
    }
}

__global__ __launch_bounds__(256)
void mergeAV_k(const float* __restrict__ Opart, const float* __restrict__ Mpart,
               const float* __restrict__ Lpart, ushort* __restrict__ AVt)
{
    int qt = blockIdx.x, h = blockIdx.y, rq = blockIdx.z;
    int t = threadIdx.x;
    int r = rq * 32 + (t >> 3), c0 = (t & 7) * 8;
    float mv[NSPLIT];
    float mstar = -INFINITY;
    #pragma unroll
    for (int s = 0; s < NSPLIT; ++s) {
        mv[s] = Mpart[((s * 2 + qt) * 8 + h) * 128 + r];
        mstar = fmaxf(mstar, mv[s]);
    }
    float wgt[NSPLIT];
    float L = 0.f;
    #pragma unroll
    for (int s = 0; s < NSPLIT; ++s) {
        wgt[s] = __expf(mv[s] - mstar);
        L += wgt[s] * Lpart[((s * 2 + qt) * 8 + h) * 128 + r];
    }
    float inv = 1.f / L;
    float acc[8] = {};
    #pragma unroll
    for (int s = 0; s < NSPLIT; ++s) {
        const float* op = Opart + (((size_t)(s * 2 + qt) * 8 + h) * 128 + r) * 64 + c0;
        #pragma unroll
        for (int e = 0; e < 8; ++e) acc[e] += wgt[s] * op[e];
    }
    #pragma unroll
    for (int e = 0; e < 8; ++e)
        AVt[((size_t)h * DH + c0 + e) * LM + qt * 128 + r] = f2b(acc[e] * inv);
}

// depthwise conv residual -> OBc bf16 [10000][512]
__global__ __launch_bounds__(256)
void conv_k(const ushort* __restrict__ Vb, const float* __restrict__ cw,
            ushort* __restrict__ OBc)
{
    int idx = blockIdx.x * 256 + threadIdx.x;
    if (idx >= NSEQ * 128) return;
    int ro = idx >> 7, c4 = idx & 127;
    int h = c4 >> 4, dq = (c4 & 15) * 4;
    int i = ro + PADR;
    float a0 = 0, a1 = 0, a2 = 0, a3 = 0;
    #pragma unroll
    for (int tt = 0; tt < 33; ++tt) {
        int src = i + tt - 16;
        if (src < NPAD) {
            float wv = cw[h * 33 + tt];
            ushort4 u = *(const ushort4*)(Vb + ((size_t)h * NPAD + src) * DH + dq);
            a0 += wv * b2f(u.x); a1 += wv * b2f(u.y);
            a2 += wv * b2f(u.z); a3 += wv * b2f(u.w);
        }
    }
    ushort4 o; o.x = f2b(a0); o.y = f2b(a1); o.z = f2b(a2); o.w = f2b(a3);
    *(ushort4*)&OBc[(size_t)ro * DMODEL + h * DH + dq] = o;
}

// fused attn1 @ W + conv residual -> OBb bf16; 64-row tiles, B-frags from L2
__global__ __launch_bounds__(256)
void outrows64(const ushort* __restrict__ Qb, const ushort* __restrict__ KLb,
               const ushort* __restrict__ WTg, const ushort* __restrict__ OBc,
               ushort* __restrict__ OBb)
{
    __shared__ __align__(16) char smem[32768];
    ushort* Qs = (ushort*)smem;   // [64][72] (overlapped by Ps)
    ushort* Ps = (ushort*)smem;   // [64][256] swizzled
    const int tid = threadIdx.x, l = tid & 63, w = tid >> 6;
    const int h = blockIdx.y, i0 = blockIdx.x * 64;
    const int lr = l & 15, lg = l >> 4;
    {   // Q tile: 64 rows x 64 cols
        int row = tid >> 2, seg = (tid & 3) * 16;
        const uint4* src = (const uint4*)(Qb + ((size_t)h * NPAD + i0 + row) * DH + seg);
        *(uint4*)&Qs[row * 72 + seg] = src[0];
        *(uint4*)&Qs[row * 72 + seg + 8] = src[1];
    }
    __syncthreads();
    f32x4 s[16];
    #pragma unroll
    for (int nf = 0; nf < 16; ++nf) s[nf] = (f32x4){0.f, 0.f, 0.f, 0.f};
    #pragma unroll
    for (int ks = 0; ks < 2; ++ks) {
        bf16x8 a = *(const bf16x8*)&Qs[(w * 16 + lr) * 72 + ks * 32 + lg * 8];
        #pragma unroll
        for (int nf = 0; nf < 16; ++nf) {
            bf16x8 b = *(const bf16x8*)(KLb + ((size_t)h * LM + nf * 16 + lr) * DH + ks * 32 + lg * 8);
            s[nf] = MFMA16(a, b, s[nf]);
        }
    }
    float inv_[4];
    #pragma unroll
    for (int i = 0; i < 4; ++i) {
        float m = s[0][i];
        #pragma unroll
        for (int nf = 1; nf < 16; ++nf) m = fmaxf(m, s[nf][i]);
        m = fmaxf(m, __shfl_xor(m, 1)); m = fmaxf(m, __shfl_xor(m, 2));
        m = fmaxf(m, __shfl_xor(m, 4)); m = fmaxf(m, __shfl_xor(m, 8));
        float sum = 0.f;
        #pragma unroll
        for (int nf = 0; nf < 16; ++nf) {
            float e = __expf(s[nf][i] - m); s[nf][i] = e; sum += e;
        }
        sum += __shfl_xor(sum, 1); sum += __shfl_xor(sum, 2);
        sum += __shfl_xor(sum, 4); sum += __shfl_xor(sum, 8);
        inv_[i] = 1.f / sum;
    }
    __syncthreads();   // all Qs reads done before Ps overwrite
    #pragma unroll
    for (int nf = 0; nf < 16; ++nf)
    #pragma unroll
    for (int i = 0; i < 4; ++i) {
        int row = w * 16 + lg * 4 + i;
        int col = nf * 16 + lr;
        Ps[row * 256 + (col ^ ((row & 7) << 3))] = f2b(s[nf][i] * inv_[i]);
    }
    // PV: wave-local rows; intra-wave LDS dependency only (no barrier needed)
    f32x4 o[4];
    #pragma unroll
    for (int nf = 0; nf < 4; ++nf) o[nf] = (f32x4){0.f, 0.f, 0.f, 0.f};
    #pragma unroll
    for (int ks = 0; ks < 8; ++ks) {
        int row = w * 16 + lr;
        int kcol = ks * 32 + lg * 8;
        bf16x8 a = *(const bf16x8*)&Ps[row * 256 + (kcol ^ ((row & 7) << 3))];
        #pragma unroll
        for (int nf = 0; nf < 4; ++nf) {
            int d = nf * 16 + lr;
            bf16x8 b = *(const bf16x8*)(WTg + ((size_t)h * DH + d) * LM + ks * 32 + lg * 8);
            o[nf] = MFMA16(a, b, o[nf]);
        }
    }
    #pragma unroll
    for (int nf = 0; nf < 4; ++nf)
    #pragma unroll
    for (int i = 0; i < 4; ++i) {
        int r = i0 + w * 16 + lg * 4 + i;
        if (r >= PADR) {
            int ro = r - PADR;
            int c = h * DH + nf * 16 + lr;
            float v = o[nf][i] + b2f(OBc[(size_t)ro * DMODEL + c]);
            OBb[(size_t)ro * DMODEL + c] = f2b(v);
        }
    }
}

// ---------------------------------------------------------------- tail ops
__global__ __launch_bounds__(256)
void edges_k(const int* __restrict__ rows, const int* __restrict__ cols,
             const float* __restrict__ vals,
             const float* __restrict__ QE, const float* __restrict__ KE,
             float* __restrict__ A_raw, int E)
{
    int gid = blockIdx.x * blockDim.x + threadIdx.x;
    int e = gid >> 6, l = gid & 63;
    if (e >= E) return;
    int r = rows[e], c = cols[e];
    const float* qp = QE + (size_t)r * DQK;
    const float* kp = KE + (size_t)c * DQK;
    float dot = 0.f;
    #pragma unroll
    for (int d = l; d < DQK; d += 64) dot += qp[d] * kp[d];
    #pragma unroll
    for (int s = 32; s > 0; s >>= 1) dot += __shfl_down(dot, s);
    if (l == 0) atomicAdd(&A_raw[r], vals[e] * dot * 0.0625f);
}

__global__ __launch_bounds__(1024)
void alphasm_k(const float* __restrict__ A_raw, float* __restrict__ alpha)
{
    __shared__ float red[1024];
    int t = threadIdx.x;
    float lm = -INFINITY;
    for (int i = t; i < NSEQ; i += 1024) lm = fmaxf(lm, A_raw[i]);
    red[t] = lm; __syncthreads();
    for (int s = 512; s > 0; s >>= 1) { if (t < s) red[t] = fmaxf(red[t], red[t + s]); __syncthreads(); }
    float mx = red[0]; __syncthreads();
    float ls = 0.f;
    for (int i = t; i < NSEQ; i += 1024) ls += __expf(A_raw[i] - mx);
    red[t] = ls; __syncthreads();
    for (int s = 512; s > 0; s >>= 1) { if (t < s) red[t] += red[t + s]; __syncthreads(); }
    float inv = 1.f / red[0];
    for (int i = t; i < NSEQ; i += 1024) alpha[i] = __expf(A_raw[i] - mx) * inv;
}

__global__ void init_k(float* __restrict__ out, const float* __restrict__ fcb,
                       unsigned int* __restrict__ mx)
{
    int t = blockIdx.x * blockDim.x + threadIdx.x;
    if (t == 0) { out[0] = fcb[0]; mx[0] = 0u; mx[1] = 0u; }
    if (t >= 1 && t <= NSEQ) out[t] = 0.f;
    if (t >= NSEQ + 1 && t < OUTSZ) out[t] = 1.0f;
}

__global__ __launch_bounds__(256)
void pooled_k(const float* __restrict__ XO, const float* __restrict__ fc,
              float* __restrict__ out0)
{
    __shared__ float red[256];
    int t = threadIdx.x;
    float acc = 0.f;
    const size_t total = (size_t)NSEQ * DMODEL;
    for (size_t idx = (size_t)blockIdx.x * 256 + t; idx < total; idx += (size_t)gridDim.x * 256) {
        int d = (int)(idx & (DMODEL - 1));
        acc += XO[idx] * fc[d];
    }
    red[t] = acc; __syncthreads();
    for (int s = 128; s > 0; s >>= 1) { if (t < s) red[t] += red[t + s]; __syncthreads(); }
    if (t == 0) atomicAdd(out0, red[0]);
}

// ---------------------------------------------------------------- launch
extern "C" void kernel_launch(void* const* d_in, const int* in_sizes, int n_in,
                              void* d_out, int out_size, void* d_ws, size_t ws_size,
                              hipStream_t stream)
{
    (void)n_in; (void)out_size; (void)ws_size;
    const float* bag   = (const float*)d_in[0];
    const int*   arow  = (const int*)d_in[1];
    const int*   acol  = (const int*)d_in[2];
    const float* aval  = (const float*)d_in[3];
    const float* w_qkv = (const float*)d_in[4];
    const float* w_out = (const float*)d_in[5];
    const float* b_out = (const float*)d_in[6];
    const float* convw = (const float*)d_in[7];
    const float* wq    = (const float*)d_in[8];
    const float* wk    = (const float*)d_in[9];
    const float* wv_w  = (const float*)d_in[10];
    const float* wv_b  = (const float*)d_in[11];
    const float* fck   = (const float*)d_in[15];
    const float* fcb   = (const float*)d_in[16];
    const int E = in_sizes[1];
    float* out = (float*)d_out;

    char* ws = (char*)d_ws;
    size_t off = 0;
    auto alloc = [&](size_t bytes) { void* p = ws + off; off += (bytes + 255) & ~(size_t)255; return p; };
    ushort* Qb    = (ushort*)alloc((size_t)HEADS * NPAD * DH * 2);
    ushort* Kb    = (ushort*)alloc((size_t)HEADS * NPAD * DH * 2);
    ushort* Vb    = (ushort*)alloc((size_t)HEADS * NPAD * DH * 2);
    ushort* bagb  = (ushort*)alloc((size_t)NSEQ * DMODEL * 2);
    ushort* wqkvT = (ushort*)alloc((size_t)1536 * 512 * 2);
    ushort* woutT = (ushort*)alloc((size_t)512 * 512 * 2);
    ushort* wqkT  = (ushort*)alloc((size_t)512 * 512 * 2);
    ushort* wvwT  = (ushort*)alloc((size_t)512 * 512 * 2);
    ushort* QLb   = (ushort*)alloc((size_t)HEADS * LM * DH * 2);
    ushort* KLb   = (ushort*)alloc((size_t)HEADS * LM * DH * 2);
    ushort* X2b   = (ushort*)alloc((size_t)HEADS * LM * LM * 2);
    ushort* Za    = (ushort*)alloc((size_t)HEADS * LM * LM * 2);
    ushort* Zat   = (ushort*)alloc((size_t)HEADS * LM * LM * 2);
    ushort* Zb2   = (ushort*)alloc((size_t)HEADS * LM * LM * 2);
    ushort* Zbt2  = (ushort*)alloc((size_t)HEADS * LM * LM * 2);
    ushort* T0    = (ushort*)alloc((size_t)HEADS * LM * LM * 2);
    ushort* T0t   = (ushort*)alloc((size_t)HEADS * LM * LM * 2);
    ushort* T1t   = (ushort*)alloc((size_t)HEADS * LM * LM * 2);
    ushort* T2t   = (ushort*)alloc((size_t)HEADS * LM * LM * 2);
    ushort* AVt   = (ushort*)alloc((size_t)HEADS * DH * LM * 2);
    ushort* WT    = (ushort*)alloc((size_t)HEADS * DH * LM * 2);
    ushort* OBc   = (ushort*)alloc((size_t)NSEQ * DMODEL * 2);
    ushort* OBb   = (ushort*)alloc((size_t)NSEQ * DMODEL * 2);
    float*  ENCf  = (float*)alloc((size_t)NSEQ * DMODEL * 4);
    ushort* ENCb  = (ushort*)alloc((size_t)NSEQ * DMODEL * 2);
    float*  ALPHA = (float*)alloc((size_t)NPAD * 4);
    float*  MXf   = (float*)alloc(256);
    unsigned int* MX = (unsigned int*)MXf;
    // aliases (disjoint lifetimes)
    float* QE = (float*)Qb;           // fp32 10000x256 (after Qb dead post-outrows)
    float* KE = (float*)Kb;           // (Kb dead post-attn3)
    float* XO = (float*)Qb;           // fp32 10000x512 spans Qb+Kb (after edges)
    // attn3 scratch aliases ENC region (written later)
    ushort* Vt    = (ushort*)ENCf;                          // 10.49 MB
    float*  Opart = (float*)ENCb;                           // 8.39 MB
    float*  Mpart = (float*)((char*)ENCb + 8388608);
    float*  Lpart = (float*)((char*)ENCb + 8519680);

    init_k<<<(OUTSZ + 255) / 256, 256, 0, stream>>>(out, fcb, MX);

    cvt_k<<<(NSEQ * DMODEL / 4 + 255) / 256, 256, 0, stream>>>(bag, bagb, NSEQ * DMODEL / 4);
    wtrans_k<<<dim3(96, 16), 256, 0, stream>>>(w_qkv, w_out, wq, wk, wv_w,
                                               wqkvT, woutT, wqkT, wvwT);

    // QKV projection (+ V^T pack), XCD-chunked grid (12 col x 80 row tiles)
    mgemm<0><<<960, 256, 0, stream>>>(
        bagb, wqkvT, NPAD, 1536, 512, PADR, 12,
        Qb, Kb, Vb, Vt, nullptr, nullptr, nullptr);

    landmark_k<<<HEADS * LM, DH, 0, stream>>>(Qb, QLb);
    landmark_k<<<HEADS * LM, DH, 0, stream>>>(Kb, KLb);

    attn2_k<<<dim3(LM, HEADS), 256, 0, stream>>>(QLb, KLb, X2b);
    colrow_k<<<HEADS, 256, 0, stream>>>(X2b, MX);
    zinit_k<<<dim3(LM, HEADS), 256, 0, stream>>>(X2b, MXf, Za, Zat);

    // Newton-Schulz pinv: one-shot-K kernels
    ushort *Z = Za, *Zt = Zat, *Zn = Zb2, *Znt = Zbt2;
    for (int it = 0; it < 6; ++it) {
        pinv_k<true,  false><<<dim3(4, 4, HEADS), 256, 0, stream>>>(
            X2b, Zt, LM, 0.f, 1.f, T0, T0t);
        pinv_k<false, true ><<<dim3(4, 4, HEADS), 256, 0, stream>>>(
            T0, T0t, LM, 7.f, 1.f, nullptr, T1t);
        pinv_k<false, true ><<<dim3(4, 4, HEADS), 256, 0, stream>>>(
            T0, T1t, LM, 15.f, 1.f, nullptr, T2t);
        pinv_k<true,  true ><<<dim3(4, 4, HEADS), 256, 0, stream>>>(
            Z, T2t, LM, 13.f, 0.25f, Zn, Znt);
        ushort* t;
        t = Z; Z = Zn; Zn = t;
        t = Zt; Zt = Znt; Znt = t;
    }

    // attn3 @ v (flash, split-KV) -> merge -> AVt; then W^T = (Z @ AV)^T
    attn3_fa<<<dim3(NSPLIT, 2, HEADS), 256, 0, stream>>>(QLb, Kb, Vt, Opart, Mpart, Lpart);
    mergeAV_k<<<dim3(2, HEADS, 4), 256, 0, stream>>>(Opart, Mpart, Lpart, AVt);
    pinv_k<false, false><<<dim3(1, 4, HEADS), 256, 0, stream>>>(
        Z, AVt, DH, 0.f, 1.f, nullptr, WT);

    // conv residual (bf16), then fused attn1 @ W + residual
    conv_k<<<(NSEQ * 128 + 255) / 256, 256, 0, stream>>>(Vb, convw, OBc);
    outrows64<<<dim3(NPAD / 64, HEADS), 256, 0, stream>>>(Qb, KLb, WT, OBc, OBb);

    // enc = out_buf @ w_out + b_out + bag
    mgemm<1><<<316, 256, 0, stream>>>(
        OBb, woutT, NSEQ, DMODEL, 512, 0, 4,
        ENCf, ENCb, nullptr, nullptr, b_out, bag, nullptr);

    // qe & ke in one GEMM (concatenated weights)
    mgemm<6><<<316, 256, 0, stream>>>(
        ENCb, wqkT, NSEQ, 512, 512, 0, 4,
        QE, KE, nullptr, nullptr, nullptr, nullptr, nullptr);

    // sparse edges -> A_raw, softmax -> alpha
    edges_k<<<(E * 64 + 255) / 256, 256, 0, stream>>>(arow, acol, aval, QE, KE, out + 1, E);
    alphasm_k<<<1, 1024, 0, stream>>>(out + 1, ALPHA);

    // value + xo epilogue
    mgemm<3><<<316, 256, 0, stream>>>(
        bagb, wvwT, NSEQ, DMODEL, 512, 0, 4,
        XO, nullptr, nullptr, nullptr, wv_b, ENCf, ALPHA);

    pooled_k<<<160, 256, 0, stream>>>(XO, fck, out);
}